// Round 7
// baseline (1038.622 us; speedup 1.0000x reference)
//
#include <hip/hip_runtime.h>
#include <cmath>

using f32x4 = __attribute__((ext_vector_type(4))) float;
using f16x8 = __attribute__((ext_vector_type(8))) _Float16;

#define SCL_H  256.0f
#define INV_HH (1.0f/65536.0f)

// ---------------- workspace layout (float units) ----------------
#define WS_ZH   ((size_t)0)
#define WS_ZL   ((size_t)4194304)
#define WS_EH   ((size_t)8388608)
#define WS_EL   ((size_t)12582912)
#define WS_Z2T  ((size_t)16777216)
#define WS_Z2G  ((size_t)16785408)
#define WS_E2T  ((size_t)16793600)
#define WS_E2G  ((size_t)16801792)
// partials: [row 8192][nj 128]
#define WS_PM   ((size_t)16809984)
#define WS_PZ   ((size_t)17858560)
#define WS_PS1  ((size_t)18907136)
#define WS_PDT  ((size_t)19955712)
#define WS_PDG  ((size_t)21004288)
#define WS_PD1  ((size_t)22052864)
#define WS_PD2  ((size_t)23101440)
#define WS_PI1  ((size_t)24150016)
#define WS_PI2  ((size_t)25198592)
#define WS_PSC  ((size_t)26247168)
#define WS_LSE  ((size_t)27295744)
#define WS_IDX  ((size_t)27303936)
#define WS_RENT ((size_t)27312128)
#define WS_RDT  ((size_t)27320320)
#define WS_RDG  ((size_t)27328512)
#define WS_GVQ  ((size_t)27336704)
#define WS_AVG4 ((size_t)27344896)
#define WS_QM   ((size_t)27418624)
#define WS_STORE_END ((size_t)60973056)

// ---------------- output layout (floats) ----------------
#define O_VQ  ((size_t)8388608)
#define O_CM  ((size_t)8388609)
#define O_ENT ((size_t)8388610)
#define O_TD  ((size_t)8388611)
#define O_GD  ((size_t)8388612)
#define O_ZT  ((size_t)8388613)
#define O_ZG  ((size_t)12582917)
#define O_IX  ((size_t)16777221)

__device__ __forceinline__ size_t tiled_off(int row, int chunk) {
    // chunk = k/8 in [0,128). layout: [rowblk][kt][slot][row&127][8]
    return (((size_t)(row >> 7) * 32 + (chunk >> 2)) * 4 + (size_t)(chunk & 3)) * 1024
           + (size_t)(row & 127) * 8;
}

__device__ __forceinline__ void gload16(const void* g, void* l) {
    __builtin_amdgcn_global_load_lds(
        (const __attribute__((address_space(1))) unsigned int*)g,
        (__attribute__((address_space(3))) unsigned int*)l, 16, 0, 0);
}

__device__ __forceinline__ f32x4 mfma16(f16x8 a, f16x8 b, f32x4 c) {
    return __builtin_amdgcn_mfma_f32_16x16x32_f16(a, b, c, 0, 0, 0);
}

__device__ __forceinline__ unsigned short f2bf(float x) {
    unsigned int u = __float_as_uint(x);
    return (unsigned short)((u + 0x7fffu + ((u >> 16) & 1u)) >> 16);
}
__device__ __forceinline__ float bf2f(unsigned short u) {
    return __uint_as_float(((unsigned int)u) << 16);
}

__device__ __forceinline__ bool dless(float a, int ia, float b, int ib) {
    return a < b || (a == b && ia < ib);
}
__device__ __forceinline__ void top2_point(float& d1, int& i1, float& d2, int& i2,
                                           float d, int j) {
    if (dless(d, j, d1, i1)) { d2 = d1; i2 = i1; d1 = d; i1 = j; }
    else if (dless(d, j, d2, i2)) { d2 = d; i2 = j; }
}
__device__ __forceinline__ void top2_merge(float& d1, int& i1, float& d2, int& i2,
                                           float od1, int oi1, float od2, int oi2) {
    if (dless(od1, oi1, d1, i1)) {
        float nd2; int ni2;
        if (dless(d1, i1, od2, oi2)) { nd2 = d1; ni2 = i1; } else { nd2 = od2; ni2 = oi2; }
        d1 = od1; i1 = oi1; d2 = nd2; i2 = ni2;
    } else if (dless(od1, oi1, d2, i2)) {
        d2 = od1; i2 = oi1;
    }
}

__global__ __launch_bounds__(256) void k_zero(float* __restrict__ p, int n) {
    int i = blockIdx.x * 256 + threadIdx.x;
    if (i < n) p[i] = 0.0f;
}

// ---- normalize z rows (halves independently); tiled fp16 hi/lo + sq-sums ----
__global__ __launch_bounds__(1024) void k_norm_z(const float* __restrict__ z,
        _Float16* __restrict__ zh, _Float16* __restrict__ zl,
        float* __restrict__ z2t, float* __restrict__ z2g) {
    int t = threadIdx.x;
    int r8 = t & 7, ck = t >> 3;
    int row = blockIdx.x * 8 + r8;
    const float* src = z + (size_t)row * 1024 + (size_t)ck * 8;
    float4 v0 = *(const float4*)src;
    float4 v1 = *(const float4*)(src + 4);
    float v[8] = {v0.x,v0.y,v0.z,v0.w,v1.x,v1.y,v1.z,v1.w};
    float ss = 0.f;
#pragma unroll
    for (int e = 0; e < 8; ++e) ss += v[e]*v[e];
    __shared__ float red[8*132];
    int ri = r8*132 + ck;
    red[ri] = ss; __syncthreads();
    for (int s = 32; s > 0; s >>= 1) { if ((ck & 63) < s) red[ri] += red[ri+s]; __syncthreads(); }
    float nrm = sqrtf(red[r8*132 + (ck & 64)]);
    float nv[8]; float s2 = 0.f;
#pragma unroll
    for (int e = 0; e < 8; ++e) { nv[e] = v[e]/nrm; s2 += nv[e]*nv[e]; }
    __syncthreads();
    red[ri] = s2; __syncthreads();
    for (int s = 32; s > 0; s >>= 1) { if ((ck & 63) < s) red[ri] += red[ri+s]; __syncthreads(); }
    if ((ck & 63) == 0) { if (ck & 64) z2g[row] = red[ri]; else z2t[row] = red[ri]; }
    f16x8 h8, l8;
#pragma unroll
    for (int e = 0; e < 8; ++e) {
        float xs = nv[e]*SCL_H;
        _Float16 h = (_Float16)xs; h8[e] = h;
        l8[e] = (_Float16)((xs - (float)h) * 4096.0f);
    }
    size_t off = tiled_off(row, ck);
    *(f16x8*)(zh + off) = h8;
    *(f16x8*)(zl + off) = l8;
}

// ---- normalize emb rows (text ck<64, graph ck>=64) ----
__global__ __launch_bounds__(1024) void k_norm_e(const float* __restrict__ et, const float* __restrict__ eg,
        _Float16* __restrict__ eh, _Float16* __restrict__ el,
        float* __restrict__ e2t, float* __restrict__ e2g) {
    int t = threadIdx.x;
    int r8 = t & 7, ck = t >> 3;
    int row = blockIdx.x * 8 + r8;
    const float* src = (ck < 64) ? (et + (size_t)row * 512 + (size_t)ck * 8)
                                 : (eg + (size_t)row * 512 + (size_t)(ck - 64) * 8);
    float4 v0 = *(const float4*)src;
    float4 v1 = *(const float4*)(src + 4);
    float v[8] = {v0.x,v0.y,v0.z,v0.w,v1.x,v1.y,v1.z,v1.w};
    float ss = 0.f;
#pragma unroll
    for (int e = 0; e < 8; ++e) ss += v[e]*v[e];
    __shared__ float red[8*132];
    int ri = r8*132 + ck;
    red[ri] = ss; __syncthreads();
    for (int s = 32; s > 0; s >>= 1) { if ((ck & 63) < s) red[ri] += red[ri+s]; __syncthreads(); }
    float nrm = sqrtf(red[r8*132 + (ck & 64)]);
    float nv[8]; float s2 = 0.f;
#pragma unroll
    for (int e = 0; e < 8; ++e) { nv[e] = v[e]/nrm; s2 += nv[e]*nv[e]; }
    __syncthreads();
    red[ri] = s2; __syncthreads();
    for (int s = 32; s > 0; s >>= 1) { if ((ck & 63) < s) red[ri] += red[ri+s]; __syncthreads(); }
    if ((ck & 63) == 0) { if (ck & 64) e2g[row] = red[ri]; else e2t[row] = red[ri]; }
    f16x8 h8, l8;
#pragma unroll
    for (int e = 0; e < 8; ++e) {
        float xs = nv[e]*SCL_H;
        _Float16 h = (_Float16)xs; h8[e] = h;
        l8[e] = (_Float16)((xs - (float)h) * 4096.0f);
    }
    size_t off = tiled_off(row, ck);
    *(f16x8*)(eh + off) = h8;
    *(f16x8*)(el + off) = l8;
}

// ---- hi-only MFMA distance GEMM: BM=128 BN=64 BK=64, 256 thr (2x2 waves), 4 blocks/CU ----
template<int PASS, bool STOREQ>
__global__ __launch_bounds__(256, 4) void k_gemm(
    const _Float16* __restrict__ zht, const _Float16* __restrict__ eht,
    const float* __restrict__ z2t, const float* __restrict__ z2g,
    const float* __restrict__ e2t, const float* __restrict__ e2g,
    float* __restrict__ pm, float* __restrict__ pz, float* __restrict__ ps1,
    float* __restrict__ pdt, float* __restrict__ pdg,
    float* __restrict__ pd1, float* __restrict__ pd2,
    int* __restrict__ pi1, int* __restrict__ pi2,
    unsigned short* __restrict__ qm,
    const float* __restrict__ lse, float* __restrict__ avgp)
{
    // bijective XCD swizzle: each XCD works 8 bi-panels x all 128 nj, nj-outer/bi-inner
    const int bid = blockIdx.x;
    const int xcd = bid & 7, local = bid >> 3;
    const int nj = local >> 3;             // [0,128)
    const int bi = xcd * 8 + (local & 7);  // [0,64)

    const int t = threadIdx.x;
    const int lane = t & 63, wid = t >> 6;
    const int wave_r = wid >> 1, wave_c = wid & 1;
    const int jf = lane & 15, g = lane >> 4;

    __shared__ __align__(16) char smem[35328];
    _Float16* lA = (_Float16*)smem;                     // 16KB [ks][slot][row128][8]
    _Float16* lB = (_Float16*)(smem + 16384);           // 8KB  [ks][slot][row64][8]
    unsigned short* sQ = (unsigned short*)smem;         // 16KB overlay (post-loop)
    float (*sM)[2]  = (float(*)[2])(smem + 24576);
    float (*sDt)[2] = (float(*)[2])(smem + 25600);
    float (*sDg)[2] = (float(*)[2])(smem + 26624);
    float (*sZ)[2]  = (float(*)[2])(smem + 27648);
    float (*sS1)[2] = (float(*)[2])(smem + 28672);
    float (*sD1)[2] = (float(*)[2])(smem + 29696);
    float (*sD2)[2] = (float(*)[2])(smem + 30720);
    int   (*sI1)[2] = (int(*)[2])(smem + 31744);
    int   (*sI2)[2] = (int(*)[2])(smem + 32768);
    float* sMf  = (float*)(smem + 33792);
    float* scol = (float*)(smem + 34304);

    if (PASS == 2 && t < 64) scol[t] = 0.f;

    f32x4 acct[4][2] = {};
    f32x4 accg[4][2] = {};

    const _Float16* pa  = zht + (size_t)bi * 131072;
    const _Float16* pbv = eht + (size_t)(nj >> 1) * 131072 + (size_t)(nj & 1) * 512;

#define STAGE(KT2) { \
        size_t kofs = (size_t)(KT2) * 8192; \
        gload16(pa + kofs + (size_t)t * 8,         lA + t * 8); \
        gload16(pa + kofs + (size_t)(256 + t) * 8, lA + (256 + t) * 8); \
        gload16(pa + kofs + (size_t)(512 + t) * 8, lA + (512 + t) * 8); \
        gload16(pa + kofs + (size_t)(768 + t) * 8, lA + (768 + t) * 8); \
        { int li = t;       gload16(pbv + kofs + (size_t)(li >> 6) * 1024 + (size_t)(li & 63) * 8, lB + li * 8); } \
        { int li = 256 + t; gload16(pbv + kofs + (size_t)(li >> 6) * 1024 + (size_t)(li & 63) * 8, lB + li * 8); } }

    for (int kt2 = 0; kt2 < 16; ++kt2) {
        STAGE(kt2)
        asm volatile("s_waitcnt vmcnt(0)" ::: "memory");
        __syncthreads();
        f16x8 a0[4], a1[4], b0[2], b1[2];
#pragma unroll
        for (int fr = 0; fr < 4; ++fr) {
            int ro = (wave_r * 64 + fr * 16 + jf) * 8;
            a0[fr] = *(const f16x8*)&lA[g * 1024 + ro];
            a1[fr] = *(const f16x8*)&lA[4096 + g * 1024 + ro];
        }
#pragma unroll
        for (int fc = 0; fc < 2; ++fc) {
            int ro = (wave_c * 32 + fc * 16 + jf) * 8;
            b0[fc] = *(const f16x8*)&lB[g * 512 + ro];
            b1[fc] = *(const f16x8*)&lB[2048 + g * 512 + ro];
        }
        if (kt2 < 8) {
#pragma unroll
            for (int fr = 0; fr < 4; ++fr)
#pragma unroll
            for (int fc = 0; fc < 2; ++fc) {
                acct[fr][fc] = mfma16(a0[fr], b0[fc], acct[fr][fc]);
                acct[fr][fc] = mfma16(a1[fr], b1[fc], acct[fr][fc]);
            }
        } else {
#pragma unroll
            for (int fr = 0; fr < 4; ++fr)
#pragma unroll
            for (int fc = 0; fc < 2; ++fc) {
                accg[fr][fc] = mfma16(a0[fr], b0[fc], accg[fr][fc]);
                accg[fr][fc] = mfma16(a1[fr], b1[fc], accg[fr][fc]);
            }
        }
        __syncthreads();
    }
#undef STAGE

    const int colbase = nj * 64 + wave_c * 32;
    float e2tc[2], e2gc[2];
#pragma unroll
    for (int fc = 0; fc < 2; ++fc) {
        e2tc[fc] = e2t[colbase + fc * 16 + jf];
        e2gc[fc] = e2g[colbase + fc * 16 + jf];
    }

    if constexpr (PASS == 1) {
        // stage 1: per-row max / top-2 / dt2 / dg2 over this wave's 32 cols; keep l in acct
#pragma unroll
        for (int fr = 0; fr < 4; ++fr) {
#pragma unroll
            for (int reg = 0; reg < 4; ++reg) {
                int rl = wave_r * 64 + fr * 16 + g * 4 + reg;
                int i  = bi * 128 + rl;
                float z2ti = z2t[i], z2gi = z2g[i];
                float mrow = -3.0e38f, dt2 = 0.f, dg2 = 0.f;
                float d1 = 3.0e38f, d2 = 3.0e38f;
                int i1 = 0x7fffffff, i2 = 0x7fffffff;
#pragma unroll
                for (int fc = 0; fc < 2; ++fc) {
                    float ht = acct[fr][fc][reg], hg = accg[fr][fc][reg];
                    float dta = z2ti + e2tc[fc] - ht * (2.0f * INV_HH);
                    float dga = z2gi + e2gc[fc] - hg * (2.0f * INV_HH);
                    float d   = dta + dga;
                    float lv  = -100.0f * d;
                    acct[fr][fc][reg] = lv;
                    dt2 += dta * dta; dg2 += dga * dga;
                    int j = colbase + fc * 16 + jf;
                    top2_point(d1, i1, d2, i2, d, j);
                    mrow = fmaxf(mrow, lv);
                }
#pragma unroll
                for (int s = 1; s < 16; s <<= 1) {
                    mrow = fmaxf(mrow, __shfl_xor(mrow, s));
                    dt2 += __shfl_xor(dt2, s);
                    dg2 += __shfl_xor(dg2, s);
                    float od1 = __shfl_xor(d1, s); int oi1 = __shfl_xor(i1, s);
                    float od2 = __shfl_xor(d2, s); int oi2 = __shfl_xor(i2, s);
                    top2_merge(d1, i1, d2, i2, od1, oi1, od2, oi2);
                }
                if (jf == 0) {
                    sM[rl][wave_c] = mrow; sDt[rl][wave_c] = dt2; sDg[rl][wave_c] = dg2;
                    sD1[rl][wave_c] = d1; sI1[rl][wave_c] = i1;
                    sD2[rl][wave_c] = d2; sI2[rl][wave_c] = i2;
                }
            }
        }
        __syncthreads();
        if (t < 128) sMf[t] = fmaxf(sM[t][0], sM[t][1]);
        __syncthreads();
        // stage 2: Z, S1 vs block max; q into LDS (overlaying dead staging buffers)
#pragma unroll
        for (int fr = 0; fr < 4; ++fr) {
#pragma unroll
            for (int reg = 0; reg < 4; ++reg) {
                int rl = wave_r * 64 + fr * 16 + g * 4 + reg;
                float M = sMf[rl];
                float Z = 0.f, S1 = 0.f;
#pragma unroll
                for (int fc = 0; fc < 2; ++fc) {
                    float lv = acct[fr][fc][reg];
                    float e  = expf(lv - M);
                    Z += e; S1 += e * lv;
                    if constexpr (STOREQ) sQ[rl * 64 + wave_c * 32 + fc * 16 + jf] = f2bf(e);
                }
#pragma unroll
                for (int s = 1; s < 16; s <<= 1) {
                    Z  += __shfl_xor(Z, s);
                    S1 += __shfl_xor(S1, s);
                }
                if (jf == 0) { sZ[rl][wave_c] = Z; sS1[rl][wave_c] = S1; }
            }
        }
        __syncthreads();
        if (t < 128) {
            float M = sMf[t];
            float Z = sZ[t][0] + sZ[t][1];
            float S1 = sS1[t][0] + sS1[t][1];
            float dt2 = sDt[t][0] + sDt[t][1];
            float dg2 = sDg[t][0] + sDg[t][1];
            float d1 = sD1[t][0], d2 = sD2[t][0];
            int i1 = sI1[t][0], i2 = sI2[t][0];
            top2_merge(d1, i1, d2, i2, sD1[t][1], sI1[t][1], sD2[t][1], sI2[t][1]);
            size_t pb = (size_t)(bi * 128 + t) * 128 + nj;
            pm[pb] = M; pz[pb] = Z; ps1[pb] = S1;
            pdt[pb] = dt2; pdg[pb] = dg2;
            pd1[pb] = d1; pd2[pb] = d2; pi1[pb] = i1; pi2[pb] = i2;
        }
        if constexpr (STOREQ) {
            // coalesced qm write-out: linear uint4 copy (no LDS bank conflicts)
            const uint4* s4 = (const uint4*)sQ;
#pragma unroll
            for (int it = 0; it < 4; ++it) {
                int f = it * 256 + t;           // [0,1024): 16KB as uint4
                int row = f >> 3, seg = f & 7;  // 8 x 16B = 128B per row
                uint4 q = s4[f];
                *(uint4*)(qm + (size_t)(bi * 128 + row) * 8192 + nj * 64 + seg * 8) = q;
            }
        }
    } else {
        // PASS 2 fallback: recompute p = exp(l - lse), column sums
        float cs0 = 0.f, cs1 = 0.f;
#pragma unroll
        for (int fr = 0; fr < 4; ++fr) {
#pragma unroll
            for (int reg = 0; reg < 4; ++reg) {
                int rl = wave_r * 64 + fr * 16 + g * 4 + reg;
                int i  = bi * 128 + rl;
                float z2ti = z2t[i], z2gi = z2g[i];
                float lsei = lse[i];
#pragma unroll
                for (int fc = 0; fc < 2; ++fc) {
                    float ht = acct[fr][fc][reg], hg = accg[fr][fc][reg];
                    float d = (z2ti + z2gi) + (e2tc[fc] + e2gc[fc])
                            - 2.0f * INV_HH * (ht + hg);
                    float lv = -100.0f * d;
                    float p = expf(lv - lsei);
                    if (fc == 0) cs0 += p; else cs1 += p;
                }
            }
        }
        cs0 += __shfl_xor(cs0, 16); cs0 += __shfl_xor(cs0, 32);
        cs1 += __shfl_xor(cs1, 16); cs1 += __shfl_xor(cs1, 32);
        if (g == 0) {
            atomicAdd(&scol[wave_c * 32 + jf], cs0);
            atomicAdd(&scol[wave_c * 32 + 16 + jf], cs1);
        }
        __syncthreads();
        if (t < 64) atomicAdd(&avgp[nj * 64 + t], scol[t]);
    }
}

// ---- merge 128 per-colblock softmax partials per row; write pscale; no atomics ----
__global__ __launch_bounds__(256) void k_rowreduce(
    const float* __restrict__ pm, const float* __restrict__ pz, const float* __restrict__ ps1,
    const float* __restrict__ pdt, const float* __restrict__ pdg,
    float* __restrict__ pscale, float* __restrict__ lse,
    float* __restrict__ rent, float* __restrict__ rdt, float* __restrict__ rdg)
{
    int b = blockIdx.x * 4 + (threadIdx.x >> 6);
    int l = threadIdx.x & 63;
    size_t i0 = (size_t)b * 128 + l, i1 = i0 + 64;
    float ma = pm[i0], mb = pm[i1];
    float m = fmaxf(ma, mb);
#pragma unroll
    for (int s = 1; s < 64; s <<= 1) m = fmaxf(m, __shfl_xor(m, s));
    float sa = expf(ma - m), sb = expf(mb - m);
    float Z  = pz[i0] * sa + pz[i1] * sb;
    float S1 = ps1[i0] * sa + ps1[i1] * sb;
    float dt2 = pdt[i0] + pdt[i1], dg2 = pdg[i0] + pdg[i1];
#pragma unroll
    for (int s = 1; s < 64; s <<= 1) {
        Z += __shfl_xor(Z, s); S1 += __shfl_xor(S1, s);
        dt2 += __shfl_xor(dt2, s); dg2 += __shfl_xor(dg2, s);
    }
    float lseb = m + logf(Z);
    pscale[i0] = expf(ma - lseb);
    pscale[i1] = expf(mb - lseb);
    if (l == 0) {
        lse[b] = lseb;
        rent[b] = lseb - S1 / Z;
        rdt[b] = dt2; rdg[b] = dg2;
    }
}

// ---- exact-argmin refinement from per-tile top-2 hi-only candidates ----
__global__ __launch_bounds__(256) void k_refine(
    const float* __restrict__ pd1, const float* __restrict__ pd2,
    const int* __restrict__ pi1, const int* __restrict__ pi2,
    const _Float16* __restrict__ zh, const _Float16* __restrict__ zl,
    const _Float16* __restrict__ eh, const _Float16* __restrict__ el,
    const float* __restrict__ z2t, const float* __restrict__ z2g,
    const float* __restrict__ e2t, const float* __restrict__ e2g,
    int* __restrict__ idxi, float* __restrict__ out)
{
    int row = blockIdx.x * 4 + (threadIdx.x >> 6);
    int l = threadIdx.x & 63;
    size_t base = (size_t)row * 128;
    float cd[4]; int ci[4];
    cd[0] = pd1[base + l];      ci[0] = pi1[base + l];
    cd[1] = pd1[base + 64 + l]; ci[1] = pi1[base + 64 + l];
    cd[2] = pd2[base + l];      ci[2] = pi2[base + l];
    cd[3] = pd2[base + 64 + l]; ci[3] = pi2[base + 64 + l];
    float M = fminf(fminf(cd[0], cd[1]), fminf(cd[2], cd[3]));
#pragma unroll
    for (int s = 1; s < 64; s <<= 1) M = fminf(M, __shfl_xor(M, s));
    const float eps = 4.0e-3f;
    unsigned long long mk[4];
#pragma unroll
    for (int k = 0; k < 4; ++k) mk[k] = __ballot(cd[k] <= M + eps);

    // preload this row's z chunks: lane l handles chunks 2l, 2l+1 (16 elems)
    float zv[16];
    {
        size_t o0 = tiled_off(row, 2 * l), o1 = tiled_off(row, 2 * l + 1);
        f16x8 h0 = *(const f16x8*)(zh + o0), l0 = *(const f16x8*)(zl + o0);
        f16x8 h1 = *(const f16x8*)(zh + o1), l1 = *(const f16x8*)(zl + o1);
#pragma unroll
        for (int e = 0; e < 8; ++e) {
            zv[e]     = (float)h0[e] * (1.0f/256.0f) + (float)l0[e] * (1.0f/1048576.0f);
            zv[8 + e] = (float)h1[e] * (1.0f/256.0f) + (float)l1[e] * (1.0f/1048576.0f);
        }
    }
    float zz = z2t[row] + z2g[row];
    float bd = 3.0e38f; int bj = 0x7fffffff;
#pragma unroll 1
    for (int k = 0; k < 4; ++k) {
        while (mk[k]) {
            int s = (int)__ffsll(mk[k]) - 1; mk[k] &= mk[k] - 1;
            int cand = __shfl(ci[k], s);
            size_t o0 = tiled_off(cand, 2 * l), o1 = tiled_off(cand, 2 * l + 1);
            f16x8 h0 = *(const f16x8*)(eh + o0), l0 = *(const f16x8*)(el + o0);
            f16x8 h1 = *(const f16x8*)(eh + o1), l1 = *(const f16x8*)(el + o1);
            float dot = 0.f;
#pragma unroll
            for (int e = 0; e < 8; ++e) {
                float ev0 = (float)h0[e] * (1.0f/256.0f) + (float)l0[e] * (1.0f/1048576.0f);
                float ev1 = (float)h1[e] * (1.0f/256.0f) + (float)l1[e] * (1.0f/1048576.0f);
                dot += zv[e] * ev0 + zv[8 + e] * ev1;
            }
#pragma unroll
            for (int s2 = 1; s2 < 64; s2 <<= 1) dot += __shfl_xor(dot, s2);
            float d = zz + e2t[cand] + e2g[cand] - 2.0f * dot;
            if (d < bd || (d == bd && cand < bj)) { bd = d; bj = cand; }
        }
    }
    if (l == 0) { idxi[row] = bj; out[O_IX + row] = (float)bj; }
}

// ---- stored-q column sums, atomic-free: 64-col blocks x 1024-row bands ----
__global__ __launch_bounds__(256) void k_colsum(const unsigned short* __restrict__ qm,
                                                const float* __restrict__ pscale,
                                                float* __restrict__ avg4) {
    int cc = blockIdx.x, rb = blockIdx.y, t = threadIdx.x;
    int cp = t & 31, rg = t >> 5;
    float a0 = 0.f, a1 = 0.f;
    const unsigned short* qb = qm + (size_t)cc * 64 + (size_t)cp * 2;
#pragma unroll 4
    for (int rr = rg; rr < 1024; rr += 8) {
        int r = rb * 1024 + rr;
        float s = pscale[(size_t)r * 128 + cc];
        unsigned int q = *(const unsigned int*)(qb + (size_t)r * 8192);
        a0 += bf2f((unsigned short)(q & 0xffffu)) * s;
        a1 += bf2f((unsigned short)(q >> 16)) * s;
    }
    __shared__ float red[512];
    red[rg * 64 + cp * 2] = a0; red[rg * 64 + cp * 2 + 1] = a1;
    __syncthreads();
    if (rg == 0) {
        float s0 = 0.f, s1 = 0.f;
#pragma unroll
        for (int k = 0; k < 8; ++k) { s0 += red[k * 64 + cp * 2]; s1 += red[k * 64 + cp * 2 + 1]; }
        avg4[(size_t)rb * 8192 + cc * 64 + cp * 2]     = s0;
        avg4[(size_t)rb * 8192 + cc * 64 + cp * 2 + 1] = s1;
    }
}

// ---- gather z_q outputs + per-row vq sums ----
__global__ __launch_bounds__(1024) void k_gather(
    const _Float16* __restrict__ zh, const _Float16* __restrict__ zl,
    const _Float16* __restrict__ eh, const _Float16* __restrict__ el,
    const int* __restrict__ idxi, float* __restrict__ out, float* __restrict__ gvq)
{
    int t = threadIdx.x;
    int r8 = t & 7, ck = t >> 3;
    int b = blockIdx.x * 8 + r8;
    int idx = idxi[b];
    size_t zo = tiled_off(b, ck), eo = tiled_off(idx, ck);
    f16x8 zh8 = *(const f16x8*)(zh + zo);
    f16x8 zl8 = *(const f16x8*)(zl + zo);
    f16x8 eh8 = *(const f16x8*)(eh + eo);
    f16x8 el8 = *(const f16x8*)(el + eo);
    float ss = 0.f; float oz[8], zq[8];
#pragma unroll
    for (int e = 0; e < 8; ++e) {
        float zn = ((float)zh8[e] + (float)zl8[e] * (1.0f / 4096.0f)) * (1.0f / SCL_H);
        float eq = ((float)eh8[e] + (float)el8[e] * (1.0f / 4096.0f)) * (1.0f / SCL_H);
        float df = eq - zn;
        zq[e] = eq; oz[e] = zn + df; ss += df * df;
    }
    float* dst = out + (size_t)b * 1024 + (size_t)ck * 8;
    *(float4*)dst       = make_float4(oz[0], oz[1], oz[2], oz[3]);
    *(float4*)(dst + 4) = make_float4(oz[4], oz[5], oz[6], oz[7]);
    float* tg = (ck < 64) ? (out + O_ZT + (size_t)b * 512 + (size_t)ck * 8)
                          : (out + O_ZG + (size_t)b * 512 + (size_t)(ck - 64) * 8);
    *(float4*)tg       = make_float4(zq[0], zq[1], zq[2], zq[3]);
    *(float4*)(tg + 4) = make_float4(zq[4], zq[5], zq[6], zq[7]);
    __shared__ float red[8*132];
    int ri = r8 * 132 + ck;
    red[ri] = ss; __syncthreads();
    for (int s = 64; s > 0; s >>= 1) { if (ck < s) red[ri] += red[ri + s]; __syncthreads(); }
    if (ck == 0) gvq[b] = red[ri];
}

__global__ __launch_bounds__(256) void k_finalize(const float* __restrict__ avg4,
        const float* __restrict__ rent, const float* __restrict__ rdt,
        const float* __restrict__ rdg, const float* __restrict__ gvq,
        float* __restrict__ out) {
    int t = threadIdx.x;
    float ent = 0.f, se = 0.f, dt = 0.f, dg = 0.f, vq = 0.f;
    for (int n = t; n < 8192; n += 256) {
        float a = 0.f;
#pragma unroll
        for (int k = 0; k < 8; ++k) a += avg4[(size_t)k * 8192 + n];
        a *= (1.0f / 8192.0f);
        ent -= a * logf(a + 1e-5f);
        se += rent[n]; dt += rdt[n]; dg += rdg[n]; vq += gvq[n];
    }
    __shared__ float red[256];
#define RED(x) { red[t] = x; __syncthreads(); \
    for (int s = 128; s > 0; s >>= 1) { if (t < s) red[t] += red[t + s]; __syncthreads(); } \
    x = red[0]; __syncthreads(); }
    RED(ent) RED(se) RED(dt) RED(dg) RED(vq)
#undef RED
    if (t == 0) {
        float vqm = vq * (1.0f / 8388608.0f);
        out[O_VQ]  = vqm;
        out[O_CM]  = 0.25f * vqm;
        out[O_ENT] = 0.1f * (se * (1.0f / 8192.0f) - ent);
        out[O_TD]  = dt * (1.0f / 8192.0f);
        out[O_GD]  = dg * (1.0f / 8192.0f);
    }
}

extern "C" void kernel_launch(void* const* d_in, const int* in_sizes, int n_in,
                              void* d_out, int out_size, void* d_ws, size_t ws_size,
                              hipStream_t stream) {
    const float* z  = (const float*)d_in[0];
    const float* et = (const float*)d_in[1];
    const float* eg = (const float*)d_in[2];
    float* out = (float*)d_out;
    float* ws  = (float*)d_ws;

    _Float16* zh = (_Float16*)(ws + WS_ZH);
    _Float16* zl = (_Float16*)(ws + WS_ZL);
    _Float16* eh = (_Float16*)(ws + WS_EH);
    _Float16* el = (_Float16*)(ws + WS_EL);
    float* z2t = ws + WS_Z2T;
    float* z2g = ws + WS_Z2G;
    float* e2t = ws + WS_E2T;
    float* e2g = ws + WS_E2G;
    float* pm  = ws + WS_PM;
    float* pz  = ws + WS_PZ;
    float* ps1 = ws + WS_PS1;
    float* pdt = ws + WS_PDT;
    float* pdg = ws + WS_PDG;
    float* pd1 = ws + WS_PD1;
    float* pd2 = ws + WS_PD2;
    int*   pi1 = (int*)(ws + WS_PI1);
    int*   pi2 = (int*)(ws + WS_PI2);
    float* psc = ws + WS_PSC;
    float* lsep = ws + WS_LSE;
    int*   idxi = (int*)(ws + WS_IDX);
    float* rent = ws + WS_RENT;
    float* rdt  = ws + WS_RDT;
    float* rdg  = ws + WS_RDG;
    float* gvq  = ws + WS_GVQ;
    float* avg4 = ws + WS_AVG4;
    unsigned short* qm = (unsigned short*)(ws + WS_QM);

    bool storeq = (ws_size >= WS_STORE_END * sizeof(float));

    k_norm_z<<<1024, 1024, 0, stream>>>(z, zh, zl, z2t, z2g);
    k_norm_e<<<1024, 1024, 0, stream>>>(et, eg, eh, el, e2t, e2g);

    if (storeq) {
        k_gemm<1, true><<<8192, 256, 0, stream>>>(zh, eh, z2t, z2g, e2t, e2g,
                                                  pm, pz, ps1, pdt, pdg,
                                                  pd1, pd2, pi1, pi2, qm, lsep, avg4);
    } else {
        k_gemm<1, false><<<8192, 256, 0, stream>>>(zh, eh, z2t, z2g, e2t, e2g,
                                                   pm, pz, ps1, pdt, pdg,
                                                   pd1, pd2, pi1, pi2, qm, lsep, avg4);
    }
    k_rowreduce<<<2048, 256, 0, stream>>>(pm, pz, ps1, pdt, pdg,
                                          psc, lsep, rent, rdt, rdg);
    k_refine<<<2048, 256, 0, stream>>>(pd1, pd2, pi1, pi2, zh, zl, eh, el,
                                       z2t, z2g, e2t, e2g, idxi, out);
    if (storeq) {
        k_colsum<<<dim3(128, 8), 256, 0, stream>>>(qm, psc, avg4);
    } else {
        k_zero<<<256, 256, 0, stream>>>(avg4, 65536);
        k_gemm<2, false><<<8192, 256, 0, stream>>>(zh, eh, z2t, z2g, e2t, e2g,
                                                   pm, pz, ps1, pdt, pdg,
                                                   pd1, pd2, pi1, pi2, qm, lsep, avg4);
    }
    k_gather<<<1024, 1024, 0, stream>>>(zh, zl, eh, el, idxi, out, gvq);
    k_finalize<<<1, 256, 0, stream>>>(avg4, rent, rdt, rdg, gvq, out);
}

// Round 8
// 1030.297 us; speedup vs baseline: 1.0081x; 1.0081x over previous
//
#include <hip/hip_runtime.h>
#include <cmath>

using f32x4 = __attribute__((ext_vector_type(4))) float;
using f16x8 = __attribute__((ext_vector_type(8))) _Float16;

#define SCL_H  256.0f
#define INV_HH (1.0f/65536.0f)

// ---------------- workspace layout (float units) ----------------
#define WS_ZH   ((size_t)0)
#define WS_ZL   ((size_t)4194304)
#define WS_EH   ((size_t)8388608)
#define WS_EL   ((size_t)12582912)
#define WS_Z2T  ((size_t)16777216)
#define WS_Z2G  ((size_t)16785408)
#define WS_E2T  ((size_t)16793600)
#define WS_E2G  ((size_t)16801792)
// partials: [nj 128][row 8192]  (contiguous in row -> coalesced block writes)
#define WS_PM   ((size_t)16809984)
#define WS_PZ   ((size_t)17858560)
#define WS_PS1  ((size_t)18907136)
#define WS_PDT  ((size_t)19955712)
#define WS_PDG  ((size_t)21004288)
#define WS_PD1  ((size_t)22052864)
#define WS_PD2  ((size_t)23101440)
#define WS_PI1  ((size_t)24150016)
#define WS_PI2  ((size_t)25198592)
#define WS_PSC  ((size_t)26247168)
#define WS_LSE  ((size_t)27295744)
#define WS_IDX  ((size_t)27303936)
#define WS_RENT ((size_t)27312128)
#define WS_RDT  ((size_t)27320320)
#define WS_RDG  ((size_t)27328512)
#define WS_GVQ  ((size_t)27336704)
#define WS_AVG4 ((size_t)27344896)
#define WS_QM   ((size_t)27418624)
#define WS_STORE_END ((size_t)60973056)

// ---------------- output layout (floats) ----------------
#define O_VQ  ((size_t)8388608)
#define O_CM  ((size_t)8388609)
#define O_ENT ((size_t)8388610)
#define O_TD  ((size_t)8388611)
#define O_GD  ((size_t)8388612)
#define O_ZT  ((size_t)8388613)
#define O_ZG  ((size_t)12582917)
#define O_IX  ((size_t)16777221)

__device__ __forceinline__ size_t tiled_off(int row, int chunk) {
    // chunk = k/8 in [0,128). layout: [rowblk][kt][slot][row&127][8]
    return (((size_t)(row >> 7) * 32 + (chunk >> 2)) * 4 + (size_t)(chunk & 3)) * 1024
           + (size_t)(row & 127) * 8;
}

__device__ __forceinline__ void gload16(const void* g, void* l) {
    __builtin_amdgcn_global_load_lds(
        (const __attribute__((address_space(1))) unsigned int*)g,
        (__attribute__((address_space(3))) unsigned int*)l, 16, 0, 0);
}

__device__ __forceinline__ f32x4 mfma16(f16x8 a, f16x8 b, f32x4 c) {
    return __builtin_amdgcn_mfma_f32_16x16x32_f16(a, b, c, 0, 0, 0);
}

__device__ __forceinline__ unsigned short f2bf(float x) {
    unsigned int u = __float_as_uint(x);
    return (unsigned short)((u + 0x7fffu + ((u >> 16) & 1u)) >> 16);
}
__device__ __forceinline__ float bf2f(unsigned short u) {
    return __uint_as_float(((unsigned int)u) << 16);
}

__device__ __forceinline__ bool dless(float a, int ia, float b, int ib) {
    return a < b || (a == b && ia < ib);
}
__device__ __forceinline__ void top2_point(float& d1, int& i1, float& d2, int& i2,
                                           float d, int j) {
    if (dless(d, j, d1, i1)) { d2 = d1; i2 = i1; d1 = d; i1 = j; }
    else if (dless(d, j, d2, i2)) { d2 = d; i2 = j; }
}
__device__ __forceinline__ void top2_merge(float& d1, int& i1, float& d2, int& i2,
                                           float od1, int oi1, float od2, int oi2) {
    if (dless(od1, oi1, d1, i1)) {
        float nd2; int ni2;
        if (dless(d1, i1, od2, oi2)) { nd2 = d1; ni2 = i1; } else { nd2 = od2; ni2 = oi2; }
        d1 = od1; i1 = oi1; d2 = nd2; i2 = ni2;
    } else if (dless(od1, oi1, d2, i2)) {
        d2 = od1; i2 = oi1;
    }
}

__global__ __launch_bounds__(256) void k_zero(float* __restrict__ p, int n) {
    int i = blockIdx.x * 256 + threadIdx.x;
    if (i < n) p[i] = 0.0f;
}

// ---- normalize z rows (halves independently); tiled fp16 hi/lo + sq-sums ----
__global__ __launch_bounds__(1024) void k_norm_z(const float* __restrict__ z,
        _Float16* __restrict__ zh, _Float16* __restrict__ zl,
        float* __restrict__ z2t, float* __restrict__ z2g) {
    int t = threadIdx.x;
    int r8 = t & 7, ck = t >> 3;
    int row = blockIdx.x * 8 + r8;
    const float* src = z + (size_t)row * 1024 + (size_t)ck * 8;
    float4 v0 = *(const float4*)src;
    float4 v1 = *(const float4*)(src + 4);
    float v[8] = {v0.x,v0.y,v0.z,v0.w,v1.x,v1.y,v1.z,v1.w};
    float ss = 0.f;
#pragma unroll
    for (int e = 0; e < 8; ++e) ss += v[e]*v[e];
    __shared__ float red[8*132];
    int ri = r8*132 + ck;
    red[ri] = ss; __syncthreads();
    for (int s = 32; s > 0; s >>= 1) { if ((ck & 63) < s) red[ri] += red[ri+s]; __syncthreads(); }
    float nrm = sqrtf(red[r8*132 + (ck & 64)]);
    float nv[8]; float s2 = 0.f;
#pragma unroll
    for (int e = 0; e < 8; ++e) { nv[e] = v[e]/nrm; s2 += nv[e]*nv[e]; }
    __syncthreads();
    red[ri] = s2; __syncthreads();
    for (int s = 32; s > 0; s >>= 1) { if ((ck & 63) < s) red[ri] += red[ri+s]; __syncthreads(); }
    if ((ck & 63) == 0) { if (ck & 64) z2g[row] = red[ri]; else z2t[row] = red[ri]; }
    f16x8 h8, l8;
#pragma unroll
    for (int e = 0; e < 8; ++e) {
        float xs = nv[e]*SCL_H;
        _Float16 h = (_Float16)xs; h8[e] = h;
        l8[e] = (_Float16)((xs - (float)h) * 4096.0f);
    }
    size_t off = tiled_off(row, ck);
    *(f16x8*)(zh + off) = h8;
    *(f16x8*)(zl + off) = l8;
}

// ---- normalize emb rows (text ck<64, graph ck>=64) ----
__global__ __launch_bounds__(1024) void k_norm_e(const float* __restrict__ et, const float* __restrict__ eg,
        _Float16* __restrict__ eh, _Float16* __restrict__ el,
        float* __restrict__ e2t, float* __restrict__ e2g) {
    int t = threadIdx.x;
    int r8 = t & 7, ck = t >> 3;
    int row = blockIdx.x * 8 + r8;
    const float* src = (ck < 64) ? (et + (size_t)row * 512 + (size_t)ck * 8)
                                 : (eg + (size_t)row * 512 + (size_t)(ck - 64) * 8);
    float4 v0 = *(const float4*)src;
    float4 v1 = *(const float4*)(src + 4);
    float v[8] = {v0.x,v0.y,v0.z,v0.w,v1.x,v1.y,v1.z,v1.w};
    float ss = 0.f;
#pragma unroll
    for (int e = 0; e < 8; ++e) ss += v[e]*v[e];
    __shared__ float red[8*132];
    int ri = r8*132 + ck;
    red[ri] = ss; __syncthreads();
    for (int s = 32; s > 0; s >>= 1) { if ((ck & 63) < s) red[ri] += red[ri+s]; __syncthreads(); }
    float nrm = sqrtf(red[r8*132 + (ck & 64)]);
    float nv[8]; float s2 = 0.f;
#pragma unroll
    for (int e = 0; e < 8; ++e) { nv[e] = v[e]/nrm; s2 += nv[e]*nv[e]; }
    __syncthreads();
    red[ri] = s2; __syncthreads();
    for (int s = 32; s > 0; s >>= 1) { if ((ck & 63) < s) red[ri] += red[ri+s]; __syncthreads(); }
    if ((ck & 63) == 0) { if (ck & 64) e2g[row] = red[ri]; else e2t[row] = red[ri]; }
    f16x8 h8, l8;
#pragma unroll
    for (int e = 0; e < 8; ++e) {
        float xs = nv[e]*SCL_H;
        _Float16 h = (_Float16)xs; h8[e] = h;
        l8[e] = (_Float16)((xs - (float)h) * 4096.0f);
    }
    size_t off = tiled_off(row, ck);
    *(f16x8*)(eh + off) = h8;
    *(f16x8*)(el + off) = l8;
}

// ---- hi-only MFMA distance GEMM: BM=128 BN=64 BK=64, 256 thr (2x2 waves), 4 blocks/CU ----
template<int PASS, bool STOREQ>
__global__ __launch_bounds__(256, 4) void k_gemm(
    const _Float16* __restrict__ zht, const _Float16* __restrict__ eht,
    const float* __restrict__ z2t, const float* __restrict__ z2g,
    const float* __restrict__ e2t, const float* __restrict__ e2g,
    float* __restrict__ pm, float* __restrict__ pz, float* __restrict__ ps1,
    float* __restrict__ pdt, float* __restrict__ pdg,
    float* __restrict__ pd1, float* __restrict__ pd2,
    int* __restrict__ pi1, int* __restrict__ pi2,
    unsigned short* __restrict__ qm,
    const float* __restrict__ lse, float* __restrict__ avgp)
{
    // bijective XCD swizzle: each XCD works 8 bi-panels x all 128 nj, nj-outer/bi-inner
    const int bid = blockIdx.x;
    const int xcd = bid & 7, local = bid >> 3;
    const int nj = local >> 3;             // [0,128)
    const int bi = xcd * 8 + (local & 7);  // [0,64)

    const int t = threadIdx.x;
    const int lane = t & 63, wid = t >> 6;
    const int wave_r = wid >> 1, wave_c = wid & 1;
    const int jf = lane & 15, g = lane >> 4;

    __shared__ __align__(16) char smem[35328];
    _Float16* lA = (_Float16*)smem;                     // 16KB [ks][slot][row128][8]
    _Float16* lB = (_Float16*)(smem + 16384);           // 8KB  [ks][slot][row64][8]
    unsigned short* sQ = (unsigned short*)smem;         // 16KB overlay (post-loop)
    float (*sM)[2]  = (float(*)[2])(smem + 24576);
    float (*sDt)[2] = (float(*)[2])(smem + 25600);
    float (*sDg)[2] = (float(*)[2])(smem + 26624);
    float (*sZ)[2]  = (float(*)[2])(smem + 27648);
    float (*sS1)[2] = (float(*)[2])(smem + 28672);
    float (*sD1)[2] = (float(*)[2])(smem + 29696);
    float (*sD2)[2] = (float(*)[2])(smem + 30720);
    int   (*sI1)[2] = (int(*)[2])(smem + 31744);
    int   (*sI2)[2] = (int(*)[2])(smem + 32768);
    float* sMf  = (float*)(smem + 33792);
    float* scol = (float*)(smem + 34304);

    if (PASS == 2 && t < 64) scol[t] = 0.f;

    f32x4 acct[4][2] = {};
    f32x4 accg[4][2] = {};

    const _Float16* pa  = zht + (size_t)bi * 131072;
    const _Float16* pbv = eht + (size_t)(nj >> 1) * 131072 + (size_t)(nj & 1) * 512;

#define STAGE(KT2) { \
        size_t kofs = (size_t)(KT2) * 8192; \
        gload16(pa + kofs + (size_t)t * 8,         lA + t * 8); \
        gload16(pa + kofs + (size_t)(256 + t) * 8, lA + (256 + t) * 8); \
        gload16(pa + kofs + (size_t)(512 + t) * 8, lA + (512 + t) * 8); \
        gload16(pa + kofs + (size_t)(768 + t) * 8, lA + (768 + t) * 8); \
        { int li = t;       gload16(pbv + kofs + (size_t)(li >> 6) * 1024 + (size_t)(li & 63) * 8, lB + li * 8); } \
        { int li = 256 + t; gload16(pbv + kofs + (size_t)(li >> 6) * 1024 + (size_t)(li & 63) * 8, lB + li * 8); } }

    for (int kt2 = 0; kt2 < 16; ++kt2) {
        STAGE(kt2)
        asm volatile("s_waitcnt vmcnt(0)" ::: "memory");
        __syncthreads();
        f16x8 a0[4], a1[4], b0[2], b1[2];
#pragma unroll
        for (int fr = 0; fr < 4; ++fr) {
            int ro = (wave_r * 64 + fr * 16 + jf) * 8;
            a0[fr] = *(const f16x8*)&lA[g * 1024 + ro];
            a1[fr] = *(const f16x8*)&lA[4096 + g * 1024 + ro];
        }
#pragma unroll
        for (int fc = 0; fc < 2; ++fc) {
            int ro = (wave_c * 32 + fc * 16 + jf) * 8;
            b0[fc] = *(const f16x8*)&lB[g * 512 + ro];
            b1[fc] = *(const f16x8*)&lB[2048 + g * 512 + ro];
        }
        if (kt2 < 8) {
#pragma unroll
            for (int fr = 0; fr < 4; ++fr)
#pragma unroll
            for (int fc = 0; fc < 2; ++fc) {
                acct[fr][fc] = mfma16(a0[fr], b0[fc], acct[fr][fc]);
                acct[fr][fc] = mfma16(a1[fr], b1[fc], acct[fr][fc]);
            }
        } else {
#pragma unroll
            for (int fr = 0; fr < 4; ++fr)
#pragma unroll
            for (int fc = 0; fc < 2; ++fc) {
                accg[fr][fc] = mfma16(a0[fr], b0[fc], accg[fr][fc]);
                accg[fr][fc] = mfma16(a1[fr], b1[fc], accg[fr][fc]);
            }
        }
        __syncthreads();
    }
#undef STAGE

    const int colbase = nj * 64 + wave_c * 32;
    float e2tc[2], e2gc[2];
#pragma unroll
    for (int fc = 0; fc < 2; ++fc) {
        e2tc[fc] = e2t[colbase + fc * 16 + jf];
        e2gc[fc] = e2g[colbase + fc * 16 + jf];
    }

    if constexpr (PASS == 1) {
        // stage 1: per-row max / top-2 / dt2 / dg2 over this wave's 32 cols; keep l in acct
#pragma unroll
        for (int fr = 0; fr < 4; ++fr) {
#pragma unroll
            for (int reg = 0; reg < 4; ++reg) {
                int rl = wave_r * 64 + fr * 16 + g * 4 + reg;
                int i  = bi * 128 + rl;
                float z2ti = z2t[i], z2gi = z2g[i];
                float mrow = -3.0e38f, dt2 = 0.f, dg2 = 0.f;
                float d1 = 3.0e38f, d2 = 3.0e38f;
                int i1 = 0x7fffffff, i2 = 0x7fffffff;
#pragma unroll
                for (int fc = 0; fc < 2; ++fc) {
                    float ht = acct[fr][fc][reg], hg = accg[fr][fc][reg];
                    float dta = z2ti + e2tc[fc] - ht * (2.0f * INV_HH);
                    float dga = z2gi + e2gc[fc] - hg * (2.0f * INV_HH);
                    float d   = dta + dga;
                    float lv  = -100.0f * d;
                    acct[fr][fc][reg] = lv;
                    dt2 += dta * dta; dg2 += dga * dga;
                    int j = colbase + fc * 16 + jf;
                    top2_point(d1, i1, d2, i2, d, j);
                    mrow = fmaxf(mrow, lv);
                }
#pragma unroll
                for (int s = 1; s < 16; s <<= 1) {
                    mrow = fmaxf(mrow, __shfl_xor(mrow, s));
                    dt2 += __shfl_xor(dt2, s);
                    dg2 += __shfl_xor(dg2, s);
                    float od1 = __shfl_xor(d1, s); int oi1 = __shfl_xor(i1, s);
                    float od2 = __shfl_xor(d2, s); int oi2 = __shfl_xor(i2, s);
                    top2_merge(d1, i1, d2, i2, od1, oi1, od2, oi2);
                }
                if (jf == 0) {
                    sM[rl][wave_c] = mrow; sDt[rl][wave_c] = dt2; sDg[rl][wave_c] = dg2;
                    sD1[rl][wave_c] = d1; sI1[rl][wave_c] = i1;
                    sD2[rl][wave_c] = d2; sI2[rl][wave_c] = i2;
                }
            }
        }
        __syncthreads();
        if (t < 128) sMf[t] = fmaxf(sM[t][0], sM[t][1]);
        __syncthreads();
        // stage 2: Z, S1 vs block max; q into LDS (overlaying dead staging buffers)
#pragma unroll
        for (int fr = 0; fr < 4; ++fr) {
#pragma unroll
            for (int reg = 0; reg < 4; ++reg) {
                int rl = wave_r * 64 + fr * 16 + g * 4 + reg;
                float M = sMf[rl];
                float Z = 0.f, S1 = 0.f;
#pragma unroll
                for (int fc = 0; fc < 2; ++fc) {
                    float lv = acct[fr][fc][reg];
                    float e  = expf(lv - M);
                    Z += e; S1 += e * lv;
                    if constexpr (STOREQ) sQ[rl * 64 + wave_c * 32 + fc * 16 + jf] = f2bf(e);
                }
#pragma unroll
                for (int s = 1; s < 16; s <<= 1) {
                    Z  += __shfl_xor(Z, s);
                    S1 += __shfl_xor(S1, s);
                }
                if (jf == 0) { sZ[rl][wave_c] = Z; sS1[rl][wave_c] = S1; }
            }
        }
        __syncthreads();
        if (t < 128) {
            float M = sMf[t];
            float Z = sZ[t][0] + sZ[t][1];
            float S1 = sS1[t][0] + sS1[t][1];
            float dt2 = sDt[t][0] + sDt[t][1];
            float dg2 = sDg[t][0] + sDg[t][1];
            float d1 = sD1[t][0], d2 = sD2[t][0];
            int i1 = sI1[t][0], i2 = sI2[t][0];
            top2_merge(d1, i1, d2, i2, sD1[t][1], sI1[t][1], sD2[t][1], sI2[t][1]);
            // [nj][row] layout: contiguous 512B runs per array -> no RMW amplification
            size_t pb = (size_t)nj * 8192 + (bi * 128 + t);
            pm[pb] = M; pz[pb] = Z; ps1[pb] = S1;
            pdt[pb] = dt2; pdg[pb] = dg2;
            pd1[pb] = d1; pd2[pb] = d2; pi1[pb] = i1; pi2[pb] = i2;
        }
        if constexpr (STOREQ) {
            // coalesced qm write-out: linear uint4 copy, 128B full-line stores
            const uint4* s4 = (const uint4*)sQ;
#pragma unroll
            for (int it = 0; it < 4; ++it) {
                int f = it * 256 + t;           // [0,1024): 16KB as uint4
                int row = f >> 3, seg = f & 7;  // 8 x 16B = 128B per row
                uint4 q = s4[f];
                *(uint4*)(qm + (size_t)(bi * 128 + row) * 8192 + nj * 64 + seg * 8) = q;
            }
        }
    } else {
        // PASS 2 fallback: recompute p = exp(l - lse), column sums
        float cs0 = 0.f, cs1 = 0.f;
#pragma unroll
        for (int fr = 0; fr < 4; ++fr) {
#pragma unroll
            for (int reg = 0; reg < 4; ++reg) {
                int rl = wave_r * 64 + fr * 16 + g * 4 + reg;
                int i  = bi * 128 + rl;
                float z2ti = z2t[i], z2gi = z2g[i];
                float lsei = lse[i];
#pragma unroll
                for (int fc = 0; fc < 2; ++fc) {
                    float ht = acct[fr][fc][reg], hg = accg[fr][fc][reg];
                    float d = (z2ti + z2gi) + (e2tc[fc] + e2gc[fc])
                            - 2.0f * INV_HH * (ht + hg);
                    float lv = -100.0f * d;
                    float p = expf(lv - lsei);
                    if (fc == 0) cs0 += p; else cs1 += p;
                }
            }
        }
        cs0 += __shfl_xor(cs0, 16); cs0 += __shfl_xor(cs0, 32);
        cs1 += __shfl_xor(cs1, 16); cs1 += __shfl_xor(cs1, 32);
        if (g == 0) {
            atomicAdd(&scol[wave_c * 32 + jf], cs0);
            atomicAdd(&scol[wave_c * 32 + 16 + jf], cs1);
        }
        __syncthreads();
        if (t < 64) atomicAdd(&avgp[nj * 64 + t], scol[t]);
    }
}

// ---- per-row online merge over nj=0..127; coalesced [nj][row] reads ----
__global__ __launch_bounds__(256) void k_rowreduce(
    const float* __restrict__ pm, const float* __restrict__ pz, const float* __restrict__ ps1,
    const float* __restrict__ pdt, const float* __restrict__ pdg,
    float* __restrict__ pscale, float* __restrict__ lse,
    float* __restrict__ rent, float* __restrict__ rdt, float* __restrict__ rdg)
{
    int row = blockIdx.x * 256 + threadIdx.x;
    float m = -3.0e38f, Z = 0.f, S1 = 0.f, dt2 = 0.f, dg2 = 0.f;
#pragma unroll 4
    for (int nj = 0; nj < 128; ++nj) {
        size_t pb = (size_t)nj * 8192 + row;
        float m0 = pm[pb];
        if (m0 > m) {
            float sc = expf(m - m0);
            Z *= sc; S1 *= sc; m = m0;
        }
        float sc0 = expf(m0 - m);
        Z  += pz[pb] * sc0;
        S1 += ps1[pb] * sc0;
        dt2 += pdt[pb]; dg2 += pdg[pb];
    }
    float lseb = m + logf(Z);
    lse[row] = lseb;
    rent[row] = lseb - S1 / Z;
    rdt[row] = dt2; rdg[row] = dg2;
#pragma unroll 4
    for (int nj = 0; nj < 128; ++nj) {
        size_t pb = (size_t)nj * 8192 + row;
        pscale[pb] = expf(pm[pb] - lseb);
    }
}

// ---- exact-argmin refinement from per-tile top-2 hi-only candidates ----
__global__ __launch_bounds__(256) void k_refine(
    const float* __restrict__ pd1, const float* __restrict__ pd2,
    const int* __restrict__ pi1, const int* __restrict__ pi2,
    const _Float16* __restrict__ zh, const _Float16* __restrict__ zl,
    const _Float16* __restrict__ eh, const _Float16* __restrict__ el,
    const float* __restrict__ z2t, const float* __restrict__ z2g,
    const float* __restrict__ e2t, const float* __restrict__ e2g,
    int* __restrict__ idxi, float* __restrict__ out)
{
    int row = blockIdx.x * 4 + (threadIdx.x >> 6);
    int l = threadIdx.x & 63;
    size_t b0 = (size_t)l * 8192 + row, b1 = (size_t)(l + 64) * 8192 + row;
    float cd[4]; int ci[4];
    cd[0] = pd1[b0]; ci[0] = pi1[b0];
    cd[1] = pd1[b1]; ci[1] = pi1[b1];
    cd[2] = pd2[b0]; ci[2] = pi2[b0];
    cd[3] = pd2[b1]; ci[3] = pi2[b1];
    float M = fminf(fminf(cd[0], cd[1]), fminf(cd[2], cd[3]));
#pragma unroll
    for (int s = 1; s < 64; s <<= 1) M = fminf(M, __shfl_xor(M, s));
    const float eps = 4.0e-3f;
    unsigned long long mk[4];
#pragma unroll
    for (int k = 0; k < 4; ++k) mk[k] = __ballot(cd[k] <= M + eps);

    // preload this row's z chunks: lane l handles chunks 2l, 2l+1 (16 elems)
    float zv[16];
    {
        size_t o0 = tiled_off(row, 2 * l), o1 = tiled_off(row, 2 * l + 1);
        f16x8 h0 = *(const f16x8*)(zh + o0), l0 = *(const f16x8*)(zl + o0);
        f16x8 h1 = *(const f16x8*)(zh + o1), l1 = *(const f16x8*)(zl + o1);
#pragma unroll
        for (int e = 0; e < 8; ++e) {
            zv[e]     = (float)h0[e] * (1.0f/256.0f) + (float)l0[e] * (1.0f/1048576.0f);
            zv[8 + e] = (float)h1[e] * (1.0f/256.0f) + (float)l1[e] * (1.0f/1048576.0f);
        }
    }
    float zz = z2t[row] + z2g[row];
    float bd = 3.0e38f; int bj = 0x7fffffff;
#pragma unroll 1
    for (int k = 0; k < 4; ++k) {
        while (mk[k]) {
            int s = (int)__ffsll(mk[k]) - 1; mk[k] &= mk[k] - 1;
            int cand = __shfl(ci[k], s);
            size_t o0 = tiled_off(cand, 2 * l), o1 = tiled_off(cand, 2 * l + 1);
            f16x8 h0 = *(const f16x8*)(eh + o0), l0 = *(const f16x8*)(el + o0);
            f16x8 h1 = *(const f16x8*)(eh + o1), l1 = *(const f16x8*)(el + o1);
            float dot = 0.f;
#pragma unroll
            for (int e = 0; e < 8; ++e) {
                float ev0 = (float)h0[e] * (1.0f/256.0f) + (float)l0[e] * (1.0f/1048576.0f);
                float ev1 = (float)h1[e] * (1.0f/256.0f) + (float)l1[e] * (1.0f/1048576.0f);
                dot += zv[e] * ev0 + zv[8 + e] * ev1;
            }
#pragma unroll
            for (int s2 = 1; s2 < 64; s2 <<= 1) dot += __shfl_xor(dot, s2);
            float d = zz + e2t[cand] + e2g[cand] - 2.0f * dot;
            if (d < bd || (d == bd && cand < bj)) { bd = d; bj = cand; }
        }
    }
    if (l == 0) { idxi[row] = bj; out[O_IX + row] = (float)bj; }
}

// ---- stored-q column sums, atomic-free: 64-col blocks x 1024-row bands ----
__global__ __launch_bounds__(256) void k_colsum(const unsigned short* __restrict__ qm,
                                                const float* __restrict__ pscale,
                                                float* __restrict__ avg4) {
    int cc = blockIdx.x, rb = blockIdx.y, t = threadIdx.x;
    int cp = t & 31, rg = t >> 5;
    float a0 = 0.f, a1 = 0.f;
    const unsigned short* qb = qm + (size_t)cc * 64 + (size_t)cp * 2;
    const float* psb = pscale + (size_t)cc * 8192;
#pragma unroll 4
    for (int rr = rg; rr < 1024; rr += 8) {
        int r = rb * 1024 + rr;
        float s = psb[r];
        unsigned int q = *(const unsigned int*)(qb + (size_t)r * 8192);
        a0 += bf2f((unsigned short)(q & 0xffffu)) * s;
        a1 += bf2f((unsigned short)(q >> 16)) * s;
    }
    __shared__ float red[512];
    red[rg * 64 + cp * 2] = a0; red[rg * 64 + cp * 2 + 1] = a1;
    __syncthreads();
    if (rg == 0) {
        float s0 = 0.f, s1 = 0.f;
#pragma unroll
        for (int k = 0; k < 8; ++k) { s0 += red[k * 64 + cp * 2]; s1 += red[k * 64 + cp * 2 + 1]; }
        avg4[(size_t)rb * 8192 + cc * 64 + cp * 2]     = s0;
        avg4[(size_t)rb * 8192 + cc * 64 + cp * 2 + 1] = s1;
    }
}

// ---- gather z_q outputs + per-row vq sums ----
__global__ __launch_bounds__(1024) void k_gather(
    const _Float16* __restrict__ zh, const _Float16* __restrict__ zl,
    const _Float16* __restrict__ eh, const _Float16* __restrict__ el,
    const int* __restrict__ idxi, float* __restrict__ out, float* __restrict__ gvq)
{
    int t = threadIdx.x;
    int r8 = t & 7, ck = t >> 3;
    int b = blockIdx.x * 8 + r8;
    int idx = idxi[b];
    size_t zo = tiled_off(b, ck), eo = tiled_off(idx, ck);
    f16x8 zh8 = *(const f16x8*)(zh + zo);
    f16x8 zl8 = *(const f16x8*)(zl + zo);
    f16x8 eh8 = *(const f16x8*)(eh + eo);
    f16x8 el8 = *(const f16x8*)(el + eo);
    float ss = 0.f; float oz[8], zq[8];
#pragma unroll
    for (int e = 0; e < 8; ++e) {
        float zn = ((float)zh8[e] + (float)zl8[e] * (1.0f / 4096.0f)) * (1.0f / SCL_H);
        float eq = ((float)eh8[e] + (float)el8[e] * (1.0f / 4096.0f)) * (1.0f / SCL_H);
        float df = eq - zn;
        zq[e] = eq; oz[e] = zn + df; ss += df * df;
    }
    float* dst = out + (size_t)b * 1024 + (size_t)ck * 8;
    *(float4*)dst       = make_float4(oz[0], oz[1], oz[2], oz[3]);
    *(float4*)(dst + 4) = make_float4(oz[4], oz[5], oz[6], oz[7]);
    float* tg = (ck < 64) ? (out + O_ZT + (size_t)b * 512 + (size_t)ck * 8)
                          : (out + O_ZG + (size_t)b * 512 + (size_t)(ck - 64) * 8);
    *(float4*)tg       = make_float4(zq[0], zq[1], zq[2], zq[3]);
    *(float4*)(tg + 4) = make_float4(zq[4], zq[5], zq[6], zq[7]);
    __shared__ float red[8*132];
    int ri = r8 * 132 + ck;
    red[ri] = ss; __syncthreads();
    for (int s = 64; s > 0; s >>= 1) { if (ck < s) red[ri] += red[ri + s]; __syncthreads(); }
    if (ck == 0) gvq[b] = red[ri];
}

__global__ __launch_bounds__(256) void k_finalize(const float* __restrict__ avg4,
        const float* __restrict__ rent, const float* __restrict__ rdt,
        const float* __restrict__ rdg, const float* __restrict__ gvq,
        float* __restrict__ out) {
    int t = threadIdx.x;
    float ent = 0.f, se = 0.f, dt = 0.f, dg = 0.f, vq = 0.f;
    for (int n = t; n < 8192; n += 256) {
        float a = 0.f;
#pragma unroll
        for (int k = 0; k < 8; ++k) a += avg4[(size_t)k * 8192 + n];
        a *= (1.0f / 8192.0f);
        ent -= a * logf(a + 1e-5f);
        se += rent[n]; dt += rdt[n]; dg += rdg[n]; vq += gvq[n];
    }
    __shared__ float red[256];
#define RED(x) { red[t] = x; __syncthreads(); \
    for (int s = 128; s > 0; s >>= 1) { if (t < s) red[t] += red[t + s]; __syncthreads(); } \
    x = red[0]; __syncthreads(); }
    RED(ent) RED(se) RED(dt) RED(dg) RED(vq)
#undef RED
    if (t == 0) {
        float vqm = vq * (1.0f / 8388608.0f);
        out[O_VQ]  = vqm;
        out[O_CM]  = 0.25f * vqm;
        out[O_ENT] = 0.1f * (se * (1.0f / 8192.0f) - ent);
        out[O_TD]  = dt * (1.0f / 8192.0f);
        out[O_GD]  = dg * (1.0f / 8192.0f);
    }
}

extern "C" void kernel_launch(void* const* d_in, const int* in_sizes, int n_in,
                              void* d_out, int out_size, void* d_ws, size_t ws_size,
                              hipStream_t stream) {
    const float* z  = (const float*)d_in[0];
    const float* et = (const float*)d_in[1];
    const float* eg = (const float*)d_in[2];
    float* out = (float*)d_out;
    float* ws  = (float*)d_ws;

    _Float16* zh = (_Float16*)(ws + WS_ZH);
    _Float16* zl = (_Float16*)(ws + WS_ZL);
    _Float16* eh = (_Float16*)(ws + WS_EH);
    _Float16* el = (_Float16*)(ws + WS_EL);
    float* z2t = ws + WS_Z2T;
    float* z2g = ws + WS_Z2G;
    float* e2t = ws + WS_E2T;
    float* e2g = ws + WS_E2G;
    float* pm  = ws + WS_PM;
    float* pz  = ws + WS_PZ;
    float* ps1 = ws + WS_PS1;
    float* pdt = ws + WS_PDT;
    float* pdg = ws + WS_PDG;
    float* pd1 = ws + WS_PD1;
    float* pd2 = ws + WS_PD2;
    int*   pi1 = (int*)(ws + WS_PI1);
    int*   pi2 = (int*)(ws + WS_PI2);
    float* psc = ws + WS_PSC;
    float* lsep = ws + WS_LSE;
    int*   idxi = (int*)(ws + WS_IDX);
    float* rent = ws + WS_RENT;
    float* rdt  = ws + WS_RDT;
    float* rdg  = ws + WS_RDG;
    float* gvq  = ws + WS_GVQ;
    float* avg4 = ws + WS_AVG4;
    unsigned short* qm = (unsigned short*)(ws + WS_QM);

    bool storeq = (ws_size >= WS_STORE_END * sizeof(float));

    k_norm_z<<<1024, 1024, 0, stream>>>(z, zh, zl, z2t, z2g);
    k_norm_e<<<1024, 1024, 0, stream>>>(et, eg, eh, el, e2t, e2g);

    if (storeq) {
        k_gemm<1, true><<<8192, 256, 0, stream>>>(zh, eh, z2t, z2g, e2t, e2g,
                                                  pm, pz, ps1, pdt, pdg,
                                                  pd1, pd2, pi1, pi2, qm, lsep, avg4);
    } else {
        k_gemm<1, false><<<8192, 256, 0, stream>>>(zh, eh, z2t, z2g, e2t, e2g,
                                                   pm, pz, ps1, pdt, pdg,
                                                   pd1, pd2, pi1, pi2, qm, lsep, avg4);
    }
    k_rowreduce<<<32, 256, 0, stream>>>(pm, pz, ps1, pdt, pdg,
                                        psc, lsep, rent, rdt, rdg);
    k_refine<<<2048, 256, 0, stream>>>(pd1, pd2, pi1, pi2, zh, zl, eh, el,
                                       z2t, z2g, e2t, e2g, idxi, out);
    if (storeq) {
        k_colsum<<<dim3(128, 8), 256, 0, stream>>>(qm, psc, avg4);
    } else {
        k_zero<<<256, 256, 0, stream>>>(avg4, 65536);
        k_gemm<2, false><<<8192, 256, 0, stream>>>(zh, eh, z2t, z2g, e2t, e2g,
                                                   pm, pz, ps1, pdt, pdg,
                                                   pd1, pd2, pi1, pi2, qm, lsep, avg4);
    }
    k_gather<<<1024, 1024, 0, stream>>>(zh, zl, eh, el, idxi, out, gvq);
    k_finalize<<<1, 256, 0, stream>>>(avg4, rent, rdt, rdg, gvq, out);
}

// Round 9
// 713.007 us; speedup vs baseline: 1.4567x; 1.4450x over previous
//
#include <hip/hip_runtime.h>
#include <cmath>

using f32x4 = __attribute__((ext_vector_type(4))) float;
using f16x8 = __attribute__((ext_vector_type(8))) _Float16;

#define SCL_H  256.0f
#define INV_HH (1.0f/65536.0f)

// ---------------- workspace layout (float units) ----------------
#define WS_ZH   ((size_t)0)
#define WS_ZL   ((size_t)4194304)
#define WS_EH   ((size_t)8388608)
#define WS_EL   ((size_t)12582912)
#define WS_Z2T  ((size_t)16777216)
#define WS_Z2G  ((size_t)16785408)
#define WS_E2T  ((size_t)16793600)
#define WS_E2G  ((size_t)16801792)
// partials: [nj 128][row 8192]  (contiguous in row -> coalesced block writes)
#define WS_PM   ((size_t)16809984)
#define WS_PZ   ((size_t)17858560)
#define WS_PS1  ((size_t)18907136)
#define WS_PDT  ((size_t)19955712)
#define WS_PDG  ((size_t)21004288)
#define WS_PD1  ((size_t)22052864)
#define WS_PD2  ((size_t)23101440)
#define WS_PI1  ((size_t)24150016)
#define WS_PI2  ((size_t)25198592)
#define WS_PSC  ((size_t)26247168)
#define WS_LSE  ((size_t)27295744)
#define WS_IDX  ((size_t)27303936)
#define WS_RENT ((size_t)27312128)
#define WS_RDT  ((size_t)27320320)
#define WS_RDG  ((size_t)27328512)
#define WS_GVQ  ((size_t)27336704)
#define WS_AVG4 ((size_t)27344896)
#define WS_QM   ((size_t)27418624)
#define WS_STORE_END ((size_t)60973056)

// ---------------- output layout (floats) ----------------
#define O_VQ  ((size_t)8388608)
#define O_CM  ((size_t)8388609)
#define O_ENT ((size_t)8388610)
#define O_TD  ((size_t)8388611)
#define O_GD  ((size_t)8388612)
#define O_ZT  ((size_t)8388613)
#define O_ZG  ((size_t)12582917)
#define O_IX  ((size_t)16777221)

__device__ __forceinline__ size_t tiled_off(int row, int chunk) {
    // chunk = k/8 in [0,128). layout: [rowblk][kt][slot][row&127][8]
    return (((size_t)(row >> 7) * 32 + (chunk >> 2)) * 4 + (size_t)(chunk & 3)) * 1024
           + (size_t)(row & 127) * 8;
}

__device__ __forceinline__ void gload16(const void* g, void* l) {
    __builtin_amdgcn_global_load_lds(
        (const __attribute__((address_space(1))) unsigned int*)g,
        (__attribute__((address_space(3))) unsigned int*)l, 16, 0, 0);
}

__device__ __forceinline__ f32x4 mfma16(f16x8 a, f16x8 b, f32x4 c) {
    return __builtin_amdgcn_mfma_f32_16x16x32_f16(a, b, c, 0, 0, 0);
}

__device__ __forceinline__ unsigned short f2bf(float x) {
    unsigned int u = __float_as_uint(x);
    return (unsigned short)((u + 0x7fffu + ((u >> 16) & 1u)) >> 16);
}
__device__ __forceinline__ float bf2f(unsigned short u) {
    return __uint_as_float(((unsigned int)u) << 16);
}

__device__ __forceinline__ bool dless(float a, int ia, float b, int ib) {
    return a < b || (a == b && ia < ib);
}
__device__ __forceinline__ void top2_point(float& d1, int& i1, float& d2, int& i2,
                                           float d, int j) {
    if (dless(d, j, d1, i1)) { d2 = d1; i2 = i1; d1 = d; i1 = j; }
    else if (dless(d, j, d2, i2)) { d2 = d; i2 = j; }
}
__device__ __forceinline__ void top2_merge(float& d1, int& i1, float& d2, int& i2,
                                           float od1, int oi1, float od2, int oi2) {
    if (dless(od1, oi1, d1, i1)) {
        float nd2; int ni2;
        if (dless(d1, i1, od2, oi2)) { nd2 = d1; ni2 = i1; } else { nd2 = od2; ni2 = oi2; }
        d1 = od1; i1 = oi1; d2 = nd2; i2 = ni2;
    } else if (dless(od1, oi1, d2, i2)) {
        d2 = od1; i2 = oi1;
    }
}

__global__ __launch_bounds__(256) void k_zero(float* __restrict__ p, int n) {
    int i = blockIdx.x * 256 + threadIdx.x;
    if (i < n) p[i] = 0.0f;
}

// ---- normalize z rows (halves independently); tiled fp16 hi/lo + sq-sums ----
__global__ __launch_bounds__(1024) void k_norm_z(const float* __restrict__ z,
        _Float16* __restrict__ zh, _Float16* __restrict__ zl,
        float* __restrict__ z2t, float* __restrict__ z2g) {
    int t = threadIdx.x;
    int r8 = t & 7, ck = t >> 3;
    int row = blockIdx.x * 8 + r8;
    const float* src = z + (size_t)row * 1024 + (size_t)ck * 8;
    float4 v0 = *(const float4*)src;
    float4 v1 = *(const float4*)(src + 4);
    float v[8] = {v0.x,v0.y,v0.z,v0.w,v1.x,v1.y,v1.z,v1.w};
    float ss = 0.f;
#pragma unroll
    for (int e = 0; e < 8; ++e) ss += v[e]*v[e];
    __shared__ float red[8*132];
    int ri = r8*132 + ck;
    red[ri] = ss; __syncthreads();
    for (int s = 32; s > 0; s >>= 1) { if ((ck & 63) < s) red[ri] += red[ri+s]; __syncthreads(); }
    float nrm = sqrtf(red[r8*132 + (ck & 64)]);
    float nv[8]; float s2 = 0.f;
#pragma unroll
    for (int e = 0; e < 8; ++e) { nv[e] = v[e]/nrm; s2 += nv[e]*nv[e]; }
    __syncthreads();
    red[ri] = s2; __syncthreads();
    for (int s = 32; s > 0; s >>= 1) { if ((ck & 63) < s) red[ri] += red[ri+s]; __syncthreads(); }
    if ((ck & 63) == 0) { if (ck & 64) z2g[row] = red[ri]; else z2t[row] = red[ri]; }
    f16x8 h8, l8;
#pragma unroll
    for (int e = 0; e < 8; ++e) {
        float xs = nv[e]*SCL_H;
        _Float16 h = (_Float16)xs; h8[e] = h;
        l8[e] = (_Float16)((xs - (float)h) * 4096.0f);
    }
    size_t off = tiled_off(row, ck);
    *(f16x8*)(zh + off) = h8;
    *(f16x8*)(zl + off) = l8;
}

// ---- normalize emb rows (text ck<64, graph ck>=64) ----
__global__ __launch_bounds__(1024) void k_norm_e(const float* __restrict__ et, const float* __restrict__ eg,
        _Float16* __restrict__ eh, _Float16* __restrict__ el,
        float* __restrict__ e2t, float* __restrict__ e2g) {
    int t = threadIdx.x;
    int r8 = t & 7, ck = t >> 3;
    int row = blockIdx.x * 8 + r8;
    const float* src = (ck < 64) ? (et + (size_t)row * 512 + (size_t)ck * 8)
                                 : (eg + (size_t)row * 512 + (size_t)(ck - 64) * 8);
    float4 v0 = *(const float4*)src;
    float4 v1 = *(const float4*)(src + 4);
    float v[8] = {v0.x,v0.y,v0.z,v0.w,v1.x,v1.y,v1.z,v1.w};
    float ss = 0.f;
#pragma unroll
    for (int e = 0; e < 8; ++e) ss += v[e]*v[e];
    __shared__ float red[8*132];
    int ri = r8*132 + ck;
    red[ri] = ss; __syncthreads();
    for (int s = 32; s > 0; s >>= 1) { if ((ck & 63) < s) red[ri] += red[ri+s]; __syncthreads(); }
    float nrm = sqrtf(red[r8*132 + (ck & 64)]);
    float nv[8]; float s2 = 0.f;
#pragma unroll
    for (int e = 0; e < 8; ++e) { nv[e] = v[e]/nrm; s2 += nv[e]*nv[e]; }
    __syncthreads();
    red[ri] = s2; __syncthreads();
    for (int s = 32; s > 0; s >>= 1) { if ((ck & 63) < s) red[ri] += red[ri+s]; __syncthreads(); }
    if ((ck & 63) == 0) { if (ck & 64) e2g[row] = red[ri]; else e2t[row] = red[ri]; }
    f16x8 h8, l8;
#pragma unroll
    for (int e = 0; e < 8; ++e) {
        float xs = nv[e]*SCL_H;
        _Float16 h = (_Float16)xs; h8[e] = h;
        l8[e] = (_Float16)((xs - (float)h) * 4096.0f);
    }
    size_t off = tiled_off(row, ck);
    *(f16x8*)(eh + off) = h8;
    *(f16x8*)(el + off) = l8;
}

// ---- hi-only MFMA distance GEMM: BM=128 BN=64 BK=64, 256 thr (2x2 waves), 3 blocks/CU ----
template<int PASS, bool STOREQ>
__global__ __launch_bounds__(256, 3) void k_gemm(
    const _Float16* __restrict__ zht, const _Float16* __restrict__ eht,
    const float* __restrict__ z2t, const float* __restrict__ z2g,
    const float* __restrict__ e2t, const float* __restrict__ e2g,
    float* __restrict__ pm, float* __restrict__ pz, float* __restrict__ ps1,
    float* __restrict__ pdt, float* __restrict__ pdg,
    float* __restrict__ pd1, float* __restrict__ pd2,
    int* __restrict__ pi1, int* __restrict__ pi2,
    unsigned short* __restrict__ qm,
    const float* __restrict__ lse, float* __restrict__ avgp)
{
    // bijective XCD swizzle: each XCD works 8 bi-panels x all 128 nj, nj-outer/bi-inner
    const int bid = blockIdx.x;
    const int xcd = bid & 7, local = bid >> 3;
    const int nj = local >> 3;             // [0,128)
    const int bi = xcd * 8 + (local & 7);  // [0,64)

    const int t = threadIdx.x;
    const int lane = t & 63, wid = t >> 6;
    const int wave_r = wid >> 1, wave_c = wid & 1;
    const int jf = lane & 15, g = lane >> 4;

    __shared__ __align__(16) char smem[35328];
    _Float16* lA = (_Float16*)smem;                     // 16KB [ks][slot][row128][8]
    _Float16* lB = (_Float16*)(smem + 16384);           // 8KB  [ks][slot][row64][8]
    unsigned short* sQ = (unsigned short*)smem;         // 16KB overlay (post-loop)
    float (*sM)[2]  = (float(*)[2])(smem + 24576);
    float (*sDt)[2] = (float(*)[2])(smem + 25600);
    float (*sDg)[2] = (float(*)[2])(smem + 26624);
    float (*sZ)[2]  = (float(*)[2])(smem + 27648);
    float (*sS1)[2] = (float(*)[2])(smem + 28672);
    float (*sD1)[2] = (float(*)[2])(smem + 29696);
    float (*sD2)[2] = (float(*)[2])(smem + 30720);
    int   (*sI1)[2] = (int(*)[2])(smem + 31744);
    int   (*sI2)[2] = (int(*)[2])(smem + 32768);
    float* sMf  = (float*)(smem + 33792);
    float* scol = (float*)(smem + 34304);

    if (PASS == 2 && t < 64) scol[t] = 0.f;

    f32x4 acct[4][2] = {};
    f32x4 accg[4][2] = {};

    const _Float16* pa  = zht + (size_t)bi * 131072;
    const _Float16* pbv = eht + (size_t)(nj >> 1) * 131072 + (size_t)(nj & 1) * 512;

#define STAGE(KT2) { \
        size_t kofs = (size_t)(KT2) * 8192; \
        gload16(pa + kofs + (size_t)t * 8,         lA + t * 8); \
        gload16(pa + kofs + (size_t)(256 + t) * 8, lA + (256 + t) * 8); \
        gload16(pa + kofs + (size_t)(512 + t) * 8, lA + (512 + t) * 8); \
        gload16(pa + kofs + (size_t)(768 + t) * 8, lA + (768 + t) * 8); \
        { int li = t;       gload16(pbv + kofs + (size_t)(li >> 6) * 1024 + (size_t)(li & 63) * 8, lB + li * 8); } \
        { int li = 256 + t; gload16(pbv + kofs + (size_t)(li >> 6) * 1024 + (size_t)(li & 63) * 8, lB + li * 8); } }

    for (int kt2 = 0; kt2 < 16; ++kt2) {
        STAGE(kt2)
        asm volatile("s_waitcnt vmcnt(0)" ::: "memory");
        __syncthreads();
        f16x8 a0[4], a1[4], b0[2], b1[2];
#pragma unroll
        for (int fr = 0; fr < 4; ++fr) {
            int ro = (wave_r * 64 + fr * 16 + jf) * 8;
            a0[fr] = *(const f16x8*)&lA[g * 1024 + ro];
            a1[fr] = *(const f16x8*)&lA[4096 + g * 1024 + ro];
        }
#pragma unroll
        for (int fc = 0; fc < 2; ++fc) {
            int ro = (wave_c * 32 + fc * 16 + jf) * 8;
            b0[fc] = *(const f16x8*)&lB[g * 512 + ro];
            b1[fc] = *(const f16x8*)&lB[2048 + g * 512 + ro];
        }
        if (kt2 < 8) {
#pragma unroll
            for (int fr = 0; fr < 4; ++fr)
#pragma unroll
            for (int fc = 0; fc < 2; ++fc) {
                acct[fr][fc] = mfma16(a0[fr], b0[fc], acct[fr][fc]);
                acct[fr][fc] = mfma16(a1[fr], b1[fc], acct[fr][fc]);
            }
        } else {
#pragma unroll
            for (int fr = 0; fr < 4; ++fr)
#pragma unroll
            for (int fc = 0; fc < 2; ++fc) {
                accg[fr][fc] = mfma16(a0[fr], b0[fc], accg[fr][fc]);
                accg[fr][fc] = mfma16(a1[fr], b1[fc], accg[fr][fc]);
            }
        }
        __syncthreads();
    }
#undef STAGE

    const int colbase = nj * 64 + wave_c * 32;
    float e2tc[2], e2gc[2];
#pragma unroll
    for (int fc = 0; fc < 2; ++fc) {
        e2tc[fc] = e2t[colbase + fc * 16 + jf];
        e2gc[fc] = e2g[colbase + fc * 16 + jf];
    }

    if constexpr (PASS == 1) {
        // stage 1: per-row max / top-2 / dt2 / dg2 over this wave's 32 cols; keep l in acct
#pragma unroll
        for (int fr = 0; fr < 4; ++fr) {
#pragma unroll
            for (int reg = 0; reg < 4; ++reg) {
                int rl = wave_r * 64 + fr * 16 + g * 4 + reg;
                int i  = bi * 128 + rl;
                float z2ti = z2t[i], z2gi = z2g[i];
                float mrow = -3.0e38f, dt2 = 0.f, dg2 = 0.f;
                float d1 = 3.0e38f, d2 = 3.0e38f;
                int i1 = 0x7fffffff, i2 = 0x7fffffff;
#pragma unroll
                for (int fc = 0; fc < 2; ++fc) {
                    float ht = acct[fr][fc][reg], hg = accg[fr][fc][reg];
                    float dta = z2ti + e2tc[fc] - ht * (2.0f * INV_HH);
                    float dga = z2gi + e2gc[fc] - hg * (2.0f * INV_HH);
                    float d   = dta + dga;
                    float lv  = -100.0f * d;
                    acct[fr][fc][reg] = lv;
                    dt2 += dta * dta; dg2 += dga * dga;
                    int j = colbase + fc * 16 + jf;
                    top2_point(d1, i1, d2, i2, d, j);
                    mrow = fmaxf(mrow, lv);
                }
#pragma unroll
                for (int s = 1; s < 16; s <<= 1) {
                    mrow = fmaxf(mrow, __shfl_xor(mrow, s));
                    dt2 += __shfl_xor(dt2, s);
                    dg2 += __shfl_xor(dg2, s);
                    float od1 = __shfl_xor(d1, s); int oi1 = __shfl_xor(i1, s);
                    float od2 = __shfl_xor(d2, s); int oi2 = __shfl_xor(i2, s);
                    top2_merge(d1, i1, d2, i2, od1, oi1, od2, oi2);
                }
                if (jf == 0) {
                    sM[rl][wave_c] = mrow; sDt[rl][wave_c] = dt2; sDg[rl][wave_c] = dg2;
                    sD1[rl][wave_c] = d1; sI1[rl][wave_c] = i1;
                    sD2[rl][wave_c] = d2; sI2[rl][wave_c] = i2;
                }
            }
        }
        __syncthreads();
        if (t < 128) sMf[t] = fmaxf(sM[t][0], sM[t][1]);
        __syncthreads();
        // stage 2: Z, S1 vs block max; q into LDS (overlaying dead staging buffers)
#pragma unroll
        for (int fr = 0; fr < 4; ++fr) {
#pragma unroll
            for (int reg = 0; reg < 4; ++reg) {
                int rl = wave_r * 64 + fr * 16 + g * 4 + reg;
                float M = sMf[rl];
                float Z = 0.f, S1 = 0.f;
#pragma unroll
                for (int fc = 0; fc < 2; ++fc) {
                    float lv = acct[fr][fc][reg];
                    float e  = expf(lv - M);
                    Z += e; S1 += e * lv;
                    if constexpr (STOREQ) sQ[rl * 64 + wave_c * 32 + fc * 16 + jf] = f2bf(e);
                }
#pragma unroll
                for (int s = 1; s < 16; s <<= 1) {
                    Z  += __shfl_xor(Z, s);
                    S1 += __shfl_xor(S1, s);
                }
                if (jf == 0) { sZ[rl][wave_c] = Z; sS1[rl][wave_c] = S1; }
            }
        }
        __syncthreads();
        if (t < 128) {
            float M = sMf[t];
            float Z = sZ[t][0] + sZ[t][1];
            float S1 = sS1[t][0] + sS1[t][1];
            float dt2 = sDt[t][0] + sDt[t][1];
            float dg2 = sDg[t][0] + sDg[t][1];
            float d1 = sD1[t][0], d2 = sD2[t][0];
            int i1 = sI1[t][0], i2 = sI2[t][0];
            top2_merge(d1, i1, d2, i2, sD1[t][1], sI1[t][1], sD2[t][1], sI2[t][1]);
            // [nj][row] layout: contiguous 512B runs per array -> no RMW amplification
            size_t pb = (size_t)nj * 8192 + (bi * 128 + t);
            pm[pb] = M; pz[pb] = Z; ps1[pb] = S1;
            pdt[pb] = dt2; pdg[pb] = dg2;
            pd1[pb] = d1; pd2[pb] = d2; pi1[pb] = i1; pi2[pb] = i2;
        }
        if constexpr (STOREQ) {
            // coalesced qm write-out: linear uint4 copy, 128B full-line stores
            const uint4* s4 = (const uint4*)sQ;
#pragma unroll
            for (int it = 0; it < 4; ++it) {
                int f = it * 256 + t;           // [0,1024): 16KB as uint4
                int row = f >> 3, seg = f & 7;  // 8 x 16B = 128B per row
                uint4 q = s4[f];
                *(uint4*)(qm + (size_t)(bi * 128 + row) * 8192 + nj * 64 + seg * 8) = q;
            }
        }
    } else {
        // PASS 2 fallback: recompute p = exp(l - lse), column sums
        float cs0 = 0.f, cs1 = 0.f;
#pragma unroll
        for (int fr = 0; fr < 4; ++fr) {
#pragma unroll
            for (int reg = 0; reg < 4; ++reg) {
                int rl = wave_r * 64 + fr * 16 + g * 4 + reg;
                int i  = bi * 128 + rl;
                float z2ti = z2t[i], z2gi = z2g[i];
                float lsei = lse[i];
#pragma unroll
                for (int fc = 0; fc < 2; ++fc) {
                    float ht = acct[fr][fc][reg], hg = accg[fr][fc][reg];
                    float d = (z2ti + z2gi) + (e2tc[fc] + e2gc[fc])
                            - 2.0f * INV_HH * (ht + hg);
                    float lv = -100.0f * d;
                    float p = expf(lv - lsei);
                    if (fc == 0) cs0 += p; else cs1 += p;
                }
            }
        }
        cs0 += __shfl_xor(cs0, 16); cs0 += __shfl_xor(cs0, 32);
        cs1 += __shfl_xor(cs1, 16); cs1 += __shfl_xor(cs1, 32);
        if (g == 0) {
            atomicAdd(&scol[wave_c * 32 + jf], cs0);
            atomicAdd(&scol[wave_c * 32 + 16 + jf], cs1);
        }
        __syncthreads();
        if (t < 64) atomicAdd(&avgp[nj * 64 + t], scol[t]);
    }
}

// ---- per-row online merge over nj=0..127; coalesced [nj][row] reads ----
__global__ __launch_bounds__(256) void k_rowreduce(
    const float* __restrict__ pm, const float* __restrict__ pz, const float* __restrict__ ps1,
    const float* __restrict__ pdt, const float* __restrict__ pdg,
    float* __restrict__ pscale, float* __restrict__ lse,
    float* __restrict__ rent, float* __restrict__ rdt, float* __restrict__ rdg)
{
    int row = blockIdx.x * 256 + threadIdx.x;
    float m = -3.0e38f, Z = 0.f, S1 = 0.f, dt2 = 0.f, dg2 = 0.f;
#pragma unroll 4
    for (int nj = 0; nj < 128; ++nj) {
        size_t pb = (size_t)nj * 8192 + row;
        float m0 = pm[pb];
        if (m0 > m) {
            float sc = expf(m - m0);
            Z *= sc; S1 *= sc; m = m0;
        }
        float sc0 = expf(m0 - m);
        Z  += pz[pb] * sc0;
        S1 += ps1[pb] * sc0;
        dt2 += pdt[pb]; dg2 += pdg[pb];
    }
    float lseb = m + logf(Z);
    lse[row] = lseb;
    rent[row] = lseb - S1 / Z;
    rdt[row] = dt2; rdg[row] = dg2;
#pragma unroll 4
    for (int nj = 0; nj < 128; ++nj) {
        size_t pb = (size_t)nj * 8192 + row;
        pscale[pb] = expf(pm[pb] - lseb);
    }
}

// ---- exact-argmin refinement from per-tile top-2 hi-only candidates ----
__global__ __launch_bounds__(256) void k_refine(
    const float* __restrict__ pd1, const float* __restrict__ pd2,
    const int* __restrict__ pi1, const int* __restrict__ pi2,
    const _Float16* __restrict__ zh, const _Float16* __restrict__ zl,
    const _Float16* __restrict__ eh, const _Float16* __restrict__ el,
    const float* __restrict__ z2t, const float* __restrict__ z2g,
    const float* __restrict__ e2t, const float* __restrict__ e2g,
    int* __restrict__ idxi, float* __restrict__ out)
{
    int row = blockIdx.x * 4 + (threadIdx.x >> 6);
    int l = threadIdx.x & 63;
    size_t b0 = (size_t)l * 8192 + row, b1 = (size_t)(l + 64) * 8192 + row;
    float cd[4]; int ci[4];
    cd[0] = pd1[b0]; ci[0] = pi1[b0];
    cd[1] = pd1[b1]; ci[1] = pi1[b1];
    cd[2] = pd2[b0]; ci[2] = pi2[b0];
    cd[3] = pd2[b1]; ci[3] = pi2[b1];
    float M = fminf(fminf(cd[0], cd[1]), fminf(cd[2], cd[3]));
#pragma unroll
    for (int s = 1; s < 64; s <<= 1) M = fminf(M, __shfl_xor(M, s));
    const float eps = 4.0e-3f;
    unsigned long long mk[4];
#pragma unroll
    for (int k = 0; k < 4; ++k) mk[k] = __ballot(cd[k] <= M + eps);

    // preload this row's z chunks: lane l handles chunks 2l, 2l+1 (16 elems)
    float zv[16];
    {
        size_t o0 = tiled_off(row, 2 * l), o1 = tiled_off(row, 2 * l + 1);
        f16x8 h0 = *(const f16x8*)(zh + o0), l0 = *(const f16x8*)(zl + o0);
        f16x8 h1 = *(const f16x8*)(zh + o1), l1 = *(const f16x8*)(zl + o1);
#pragma unroll
        for (int e = 0; e < 8; ++e) {
            zv[e]     = (float)h0[e] * (1.0f/256.0f) + (float)l0[e] * (1.0f/1048576.0f);
            zv[8 + e] = (float)h1[e] * (1.0f/256.0f) + (float)l1[e] * (1.0f/1048576.0f);
        }
    }
    float zz = z2t[row] + z2g[row];
    float bd = 3.0e38f; int bj = 0x7fffffff;
#pragma unroll 1
    for (int k = 0; k < 4; ++k) {
        while (mk[k]) {
            int s = (int)__ffsll(mk[k]) - 1; mk[k] &= mk[k] - 1;
            int cand = __shfl(ci[k], s);
            size_t o0 = tiled_off(cand, 2 * l), o1 = tiled_off(cand, 2 * l + 1);
            f16x8 h0 = *(const f16x8*)(eh + o0), l0 = *(const f16x8*)(el + o0);
            f16x8 h1 = *(const f16x8*)(eh + o1), l1 = *(const f16x8*)(el + o1);
            float dot = 0.f;
#pragma unroll
            for (int e = 0; e < 8; ++e) {
                float ev0 = (float)h0[e] * (1.0f/256.0f) + (float)l0[e] * (1.0f/1048576.0f);
                float ev1 = (float)h1[e] * (1.0f/256.0f) + (float)l1[e] * (1.0f/1048576.0f);
                dot += zv[e] * ev0 + zv[8 + e] * ev1;
            }
#pragma unroll
            for (int s2 = 1; s2 < 64; s2 <<= 1) dot += __shfl_xor(dot, s2);
            float d = zz + e2t[cand] + e2g[cand] - 2.0f * dot;
            if (d < bd || (d == bd && cand < bj)) { bd = d; bj = cand; }
        }
    }
    if (l == 0) { idxi[row] = bj; out[O_IX + row] = (float)bj; }
}

// ---- stored-q column sums, atomic-free: 64-col blocks x 1024-row bands ----
__global__ __launch_bounds__(256) void k_colsum(const unsigned short* __restrict__ qm,
                                                const float* __restrict__ pscale,
                                                float* __restrict__ avg4) {
    int cc = blockIdx.x, rb = blockIdx.y, t = threadIdx.x;
    int cp = t & 31, rg = t >> 5;
    float a0 = 0.f, a1 = 0.f;
    const unsigned short* qb = qm + (size_t)cc * 64 + (size_t)cp * 2;
    const float* psb = pscale + (size_t)cc * 8192;
#pragma unroll 4
    for (int rr = rg; rr < 1024; rr += 8) {
        int r = rb * 1024 + rr;
        float s = psb[r];
        unsigned int q = *(const unsigned int*)(qb + (size_t)r * 8192);
        a0 += bf2f((unsigned short)(q & 0xffffu)) * s;
        a1 += bf2f((unsigned short)(q >> 16)) * s;
    }
    __shared__ float red[512];
    red[rg * 64 + cp * 2] = a0; red[rg * 64 + cp * 2 + 1] = a1;
    __syncthreads();
    if (rg == 0) {
        float s0 = 0.f, s1 = 0.f;
#pragma unroll
        for (int k = 0; k < 8; ++k) { s0 += red[k * 64 + cp * 2]; s1 += red[k * 64 + cp * 2 + 1]; }
        avg4[(size_t)rb * 8192 + cc * 64 + cp * 2]     = s0;
        avg4[(size_t)rb * 8192 + cc * 64 + cp * 2 + 1] = s1;
    }
}

// ---- gather z_q outputs + per-row vq sums ----
__global__ __launch_bounds__(1024) void k_gather(
    const _Float16* __restrict__ zh, const _Float16* __restrict__ zl,
    const _Float16* __restrict__ eh, const _Float16* __restrict__ el,
    const int* __restrict__ idxi, float* __restrict__ out, float* __restrict__ gvq)
{
    int t = threadIdx.x;
    int r8 = t & 7, ck = t >> 3;
    int b = blockIdx.x * 8 + r8;
    int idx = idxi[b];
    size_t zo = tiled_off(b, ck), eo = tiled_off(idx, ck);
    f16x8 zh8 = *(const f16x8*)(zh + zo);
    f16x8 zl8 = *(const f16x8*)(zl + zo);
    f16x8 eh8 = *(const f16x8*)(eh + eo);
    f16x8 el8 = *(const f16x8*)(el + eo);
    float ss = 0.f; float oz[8], zq[8];
#pragma unroll
    for (int e = 0; e < 8; ++e) {
        float zn = ((float)zh8[e] + (float)zl8[e] * (1.0f / 4096.0f)) * (1.0f / SCL_H);
        float eq = ((float)eh8[e] + (float)el8[e] * (1.0f / 4096.0f)) * (1.0f / SCL_H);
        float df = eq - zn;
        zq[e] = eq; oz[e] = zn + df; ss += df * df;
    }
    float* dst = out + (size_t)b * 1024 + (size_t)ck * 8;
    *(float4*)dst       = make_float4(oz[0], oz[1], oz[2], oz[3]);
    *(float4*)(dst + 4) = make_float4(oz[4], oz[5], oz[6], oz[7]);
    float* tg = (ck < 64) ? (out + O_ZT + (size_t)b * 512 + (size_t)ck * 8)
                          : (out + O_ZG + (size_t)b * 512 + (size_t)(ck - 64) * 8);
    *(float4*)tg       = make_float4(zq[0], zq[1], zq[2], zq[3]);
    *(float4*)(tg + 4) = make_float4(zq[4], zq[5], zq[6], zq[7]);
    __shared__ float red[8*132];
    int ri = r8 * 132 + ck;
    red[ri] = ss; __syncthreads();
    for (int s = 64; s > 0; s >>= 1) { if (ck < s) red[ri] += red[ri + s]; __syncthreads(); }
    if (ck == 0) gvq[b] = red[ri];
}

__global__ __launch_bounds__(256) void k_finalize(const float* __restrict__ avg4,
        const float* __restrict__ rent, const float* __restrict__ rdt,
        const float* __restrict__ rdg, const float* __restrict__ gvq,
        float* __restrict__ out) {
    int t = threadIdx.x;
    float ent = 0.f, se = 0.f, dt = 0.f, dg = 0.f, vq = 0.f;
    for (int n = t; n < 8192; n += 256) {
        float a = 0.f;
#pragma unroll
        for (int k = 0; k < 8; ++k) a += avg4[(size_t)k * 8192 + n];
        a *= (1.0f / 8192.0f);
        ent -= a * logf(a + 1e-5f);
        se += rent[n]; dt += rdt[n]; dg += rdg[n]; vq += gvq[n];
    }
    __shared__ float red[256];
#define RED(x) { red[t] = x; __syncthreads(); \
    for (int s = 128; s > 0; s >>= 1) { if (t < s) red[t] += red[t + s]; __syncthreads(); } \
    x = red[0]; __syncthreads(); }
    RED(ent) RED(se) RED(dt) RED(dg) RED(vq)
#undef RED
    if (t == 0) {
        float vqm = vq * (1.0f / 8388608.0f);
        out[O_VQ]  = vqm;
        out[O_CM]  = 0.25f * vqm;
        out[O_ENT] = 0.1f * (se * (1.0f / 8192.0f) - ent);
        out[O_TD]  = dt * (1.0f / 8192.0f);
        out[O_GD]  = dg * (1.0f / 8192.0f);
    }
}

extern "C" void kernel_launch(void* const* d_in, const int* in_sizes, int n_in,
                              void* d_out, int out_size, void* d_ws, size_t ws_size,
                              hipStream_t stream) {
    const float* z  = (const float*)d_in[0];
    const float* et = (const float*)d_in[1];
    const float* eg = (const float*)d_in[2];
    float* out = (float*)d_out;
    float* ws  = (float*)d_ws;

    _Float16* zh = (_Float16*)(ws + WS_ZH);
    _Float16* zl = (_Float16*)(ws + WS_ZL);
    _Float16* eh = (_Float16*)(ws + WS_EH);
    _Float16* el = (_Float16*)(ws + WS_EL);
    float* z2t = ws + WS_Z2T;
    float* z2g = ws + WS_Z2G;
    float* e2t = ws + WS_E2T;
    float* e2g = ws + WS_E2G;
    float* pm  = ws + WS_PM;
    float* pz  = ws + WS_PZ;
    float* ps1 = ws + WS_PS1;
    float* pdt = ws + WS_PDT;
    float* pdg = ws + WS_PDG;
    float* pd1 = ws + WS_PD1;
    float* pd2 = ws + WS_PD2;
    int*   pi1 = (int*)(ws + WS_PI1);
    int*   pi2 = (int*)(ws + WS_PI2);
    float* psc = ws + WS_PSC;
    float* lsep = ws + WS_LSE;
    int*   idxi = (int*)(ws + WS_IDX);
    float* rent = ws + WS_RENT;
    float* rdt  = ws + WS_RDT;
    float* rdg  = ws + WS_RDG;
    float* gvq  = ws + WS_GVQ;
    float* avg4 = ws + WS_AVG4;
    unsigned short* qm = (unsigned short*)(ws + WS_QM);

    bool storeq = (ws_size >= WS_STORE_END * sizeof(float));

    k_norm_z<<<1024, 1024, 0, stream>>>(z, zh, zl, z2t, z2g);
    k_norm_e<<<1024, 1024, 0, stream>>>(et, eg, eh, el, e2t, e2g);

    if (storeq) {
        k_gemm<1, true><<<8192, 256, 0, stream>>>(zh, eh, z2t, z2g, e2t, e2g,
                                                  pm, pz, ps1, pdt, pdg,
                                                  pd1, pd2, pi1, pi2, qm, lsep, avg4);
    } else {
        k_gemm<1, false><<<8192, 256, 0, stream>>>(zh, eh, z2t, z2g, e2t, e2g,
                                                   pm, pz, ps1, pdt, pdg,
                                                   pd1, pd2, pi1, pi2, qm, lsep, avg4);
    }
    k_rowreduce<<<32, 256, 0, stream>>>(pm, pz, ps1, pdt, pdg,
                                        psc, lsep, rent, rdt, rdg);
    k_refine<<<2048, 256, 0, stream>>>(pd1, pd2, pi1, pi2, zh, zl, eh, el,
                                       z2t, z2g, e2t, e2g, idxi, out);
    if (storeq) {
        k_colsum<<<dim3(128, 8), 256, 0, stream>>>(qm, psc, avg4);
    } else {
        k_zero<<<256, 256, 0, stream>>>(avg4, 65536);
        k_gemm<2, false><<<8192, 256, 0, stream>>>(zh, eh, z2t, z2g, e2t, e2g,
                                                   pm, pz, ps1, pdt, pdg,
                                                   pd1, pd2, pi1, pi2, qm, lsep, avg4);
    }
    k_gather<<<1024, 1024, 0, stream>>>(zh, zl, eh, el, idxi, out, gvq);
    k_finalize<<<1, 256, 0, stream>>>(avg4, rent, rdt, rdg, gvq, out);
}

// Round 10
// 703.832 us; speedup vs baseline: 1.4757x; 1.0130x over previous
//
#include <hip/hip_runtime.h>
#include <cmath>

using f32x4 = __attribute__((ext_vector_type(4))) float;
using f16x8 = __attribute__((ext_vector_type(8))) _Float16;

#define SCL_H  256.0f
#define INV_HH (1.0f/65536.0f)

// ---------------- workspace layout (float units) ----------------
#define WS_ZH   ((size_t)0)
#define WS_ZL   ((size_t)4194304)
#define WS_EH   ((size_t)8388608)
#define WS_EL   ((size_t)12582912)
#define WS_Z2T  ((size_t)16777216)
#define WS_Z2G  ((size_t)16785408)
#define WS_E2T  ((size_t)16793600)
#define WS_E2G  ((size_t)16801792)
// partials: [nj 128][row 8192]  (contiguous in row -> coalesced block writes)
#define WS_PM   ((size_t)16809984)
#define WS_PZ   ((size_t)17858560)
#define WS_PS1  ((size_t)18907136)
#define WS_PDT  ((size_t)19955712)
#define WS_PDG  ((size_t)21004288)
#define WS_PD1  ((size_t)22052864)
#define WS_PD2  ((size_t)23101440)
#define WS_PI1  ((size_t)24150016)
#define WS_PI2  ((size_t)25198592)
#define WS_LSE  ((size_t)26247168)
#define WS_IDX  ((size_t)26255360)
#define WS_RENT ((size_t)26263552)
#define WS_RDT  ((size_t)26271744)
#define WS_RDG  ((size_t)26279936)
#define WS_GVQ  ((size_t)26288128)
#define WS_AVG4 ((size_t)26296320)
#define WS_QM   ((size_t)26370048)
#define WS_STORE_END ((size_t)59924480)

// ---------------- output layout (floats) ----------------
#define O_VQ  ((size_t)8388608)
#define O_CM  ((size_t)8388609)
#define O_ENT ((size_t)8388610)
#define O_TD  ((size_t)8388611)
#define O_GD  ((size_t)8388612)
#define O_ZT  ((size_t)8388613)
#define O_ZG  ((size_t)12582917)
#define O_IX  ((size_t)16777221)

__device__ __forceinline__ size_t tiled_off(int row, int chunk) {
    // chunk = k/8 in [0,128). layout: [rowblk][kt][slot][row&127][8]
    return (((size_t)(row >> 7) * 32 + (chunk >> 2)) * 4 + (size_t)(chunk & 3)) * 1024
           + (size_t)(row & 127) * 8;
}

__device__ __forceinline__ void gload16(const void* g, void* l) {
    __builtin_amdgcn_global_load_lds(
        (const __attribute__((address_space(1))) unsigned int*)g,
        (__attribute__((address_space(3))) unsigned int*)l, 16, 0, 0);
}

__device__ __forceinline__ f32x4 mfma16(f16x8 a, f16x8 b, f32x4 c) {
    return __builtin_amdgcn_mfma_f32_16x16x32_f16(a, b, c, 0, 0, 0);
}

__device__ __forceinline__ unsigned short f2bf(float x) {
    unsigned int u = __float_as_uint(x);
    return (unsigned short)((u + 0x7fffu + ((u >> 16) & 1u)) >> 16);
}
__device__ __forceinline__ float bf2f(unsigned short u) {
    return __uint_as_float(((unsigned int)u) << 16);
}

__device__ __forceinline__ bool dless(float a, int ia, float b, int ib) {
    return a < b || (a == b && ia < ib);
}
__device__ __forceinline__ void top2_point(float& d1, int& i1, float& d2, int& i2,
                                           float d, int j) {
    if (dless(d, j, d1, i1)) { d2 = d1; i2 = i1; d1 = d; i1 = j; }
    else if (dless(d, j, d2, i2)) { d2 = d; i2 = j; }
}
__device__ __forceinline__ void top2_merge(float& d1, int& i1, float& d2, int& i2,
                                           float od1, int oi1, float od2, int oi2) {
    if (dless(od1, oi1, d1, i1)) {
        float nd2; int ni2;
        if (dless(d1, i1, od2, oi2)) { nd2 = d1; ni2 = i1; } else { nd2 = od2; ni2 = oi2; }
        d1 = od1; i1 = oi1; d2 = nd2; i2 = ni2;
    } else if (dless(od1, oi1, d2, i2)) {
        d2 = od1; i2 = oi1;
    }
}

__global__ __launch_bounds__(256) void k_zero(float* __restrict__ p, int n) {
    int i = blockIdx.x * 256 + threadIdx.x;
    if (i < n) p[i] = 0.0f;
}

// ---- normalize z rows (halves independently); tiled fp16 hi/lo + sq-sums ----
__global__ __launch_bounds__(1024) void k_norm_z(const float* __restrict__ z,
        _Float16* __restrict__ zh, _Float16* __restrict__ zl,
        float* __restrict__ z2t, float* __restrict__ z2g) {
    int t = threadIdx.x;
    int r8 = t & 7, ck = t >> 3;
    int row = blockIdx.x * 8 + r8;
    const float* src = z + (size_t)row * 1024 + (size_t)ck * 8;
    float4 v0 = *(const float4*)src;
    float4 v1 = *(const float4*)(src + 4);
    float v[8] = {v0.x,v0.y,v0.z,v0.w,v1.x,v1.y,v1.z,v1.w};
    float ss = 0.f;
#pragma unroll
    for (int e = 0; e < 8; ++e) ss += v[e]*v[e];
    __shared__ float red[8*132];
    int ri = r8*132 + ck;
    red[ri] = ss; __syncthreads();
    for (int s = 32; s > 0; s >>= 1) { if ((ck & 63) < s) red[ri] += red[ri+s]; __syncthreads(); }
    float nrm = sqrtf(red[r8*132 + (ck & 64)]);
    float nv[8]; float s2 = 0.f;
#pragma unroll
    for (int e = 0; e < 8; ++e) { nv[e] = v[e]/nrm; s2 += nv[e]*nv[e]; }
    __syncthreads();
    red[ri] = s2; __syncthreads();
    for (int s = 32; s > 0; s >>= 1) { if ((ck & 63) < s) red[ri] += red[ri+s]; __syncthreads(); }
    if ((ck & 63) == 0) { if (ck & 64) z2g[row] = red[ri]; else z2t[row] = red[ri]; }
    f16x8 h8, l8;
#pragma unroll
    for (int e = 0; e < 8; ++e) {
        float xs = nv[e]*SCL_H;
        _Float16 h = (_Float16)xs; h8[e] = h;
        l8[e] = (_Float16)((xs - (float)h) * 4096.0f);
    }
    size_t off = tiled_off(row, ck);
    *(f16x8*)(zh + off) = h8;
    *(f16x8*)(zl + off) = l8;
}

// ---- normalize emb rows (text ck<64, graph ck>=64) ----
__global__ __launch_bounds__(1024) void k_norm_e(const float* __restrict__ et, const float* __restrict__ eg,
        _Float16* __restrict__ eh, _Float16* __restrict__ el,
        float* __restrict__ e2t, float* __restrict__ e2g) {
    int t = threadIdx.x;
    int r8 = t & 7, ck = t >> 3;
    int row = blockIdx.x * 8 + r8;
    const float* src = (ck < 64) ? (et + (size_t)row * 512 + (size_t)ck * 8)
                                 : (eg + (size_t)row * 512 + (size_t)(ck - 64) * 8);
    float4 v0 = *(const float4*)src;
    float4 v1 = *(const float4*)(src + 4);
    float v[8] = {v0.x,v0.y,v0.z,v0.w,v1.x,v1.y,v1.z,v1.w};
    float ss = 0.f;
#pragma unroll
    for (int e = 0; e < 8; ++e) ss += v[e]*v[e];
    __shared__ float red[8*132];
    int ri = r8*132 + ck;
    red[ri] = ss; __syncthreads();
    for (int s = 32; s > 0; s >>= 1) { if ((ck & 63) < s) red[ri] += red[ri+s]; __syncthreads(); }
    float nrm = sqrtf(red[r8*132 + (ck & 64)]);
    float nv[8]; float s2 = 0.f;
#pragma unroll
    for (int e = 0; e < 8; ++e) { nv[e] = v[e]/nrm; s2 += nv[e]*nv[e]; }
    __syncthreads();
    red[ri] = s2; __syncthreads();
    for (int s = 32; s > 0; s >>= 1) { if ((ck & 63) < s) red[ri] += red[ri+s]; __syncthreads(); }
    if ((ck & 63) == 0) { if (ck & 64) e2g[row] = red[ri]; else e2t[row] = red[ri]; }
    f16x8 h8, l8;
#pragma unroll
    for (int e = 0; e < 8; ++e) {
        float xs = nv[e]*SCL_H;
        _Float16 h = (_Float16)xs; h8[e] = h;
        l8[e] = (_Float16)((xs - (float)h) * 4096.0f);
    }
    size_t off = tiled_off(row, ck);
    *(f16x8*)(eh + off) = h8;
    *(f16x8*)(el + off) = l8;
}

// ---- hi-only MFMA GEMM: BM=128 BN=64 BK=64, 2x2 waves, dbuf + counted vmcnt, 3/CU ----
template<int PASS, bool STOREQ>
__global__ __launch_bounds__(256, 3) void k_gemm(
    const _Float16* __restrict__ zht, const _Float16* __restrict__ eht,
    const float* __restrict__ z2t, const float* __restrict__ z2g,
    const float* __restrict__ e2t, const float* __restrict__ e2g,
    float* __restrict__ pm, float* __restrict__ pz, float* __restrict__ ps1,
    float* __restrict__ pdt, float* __restrict__ pdg,
    float* __restrict__ pd1, float* __restrict__ pd2,
    int* __restrict__ pi1, int* __restrict__ pi2,
    unsigned short* __restrict__ qm,
    const float* __restrict__ lse, float* __restrict__ avgp)
{
    // bijective XCD swizzle: each XCD works 8 bi-panels x all 128 nj
    const int bid = blockIdx.x;
    const int xcd = bid & 7, local = bid >> 3;
    const int nj = local >> 3;             // [0,128)
    const int bi = xcd * 8 + (local & 7);  // [0,64)

    const int t = threadIdx.x;
    const int lane = t & 63, wid = t >> 6;
    const int wave_r = wid >> 1, wave_c = wid & 1;
    const int jf = lane & 15, g = lane >> 4;

    // 48KB: two 24KB staging buffers (A 16KB + B 8KB each); epilogue overlays
    __shared__ __align__(16) char smem[49152];
    unsigned short* sQ = (unsigned short*)smem;          // 16KB overlay (post-loop)
    float (*sM)[2]  = (float(*)[2])(smem + 16384);
    float (*sDt)[2] = (float(*)[2])(smem + 17408);
    float (*sDg)[2] = (float(*)[2])(smem + 18432);
    float (*sZ)[2]  = (float(*)[2])(smem + 19456);
    float (*sS1)[2] = (float(*)[2])(smem + 20480);
    float (*sD1)[2] = (float(*)[2])(smem + 21504);
    float (*sD2)[2] = (float(*)[2])(smem + 22528);
    int   (*sI1)[2] = (int(*)[2])(smem + 23552);
    int   (*sI2)[2] = (int(*)[2])(smem + 24576);
    float* sMf  = (float*)(smem + 25600);
    float* scol = (float*)(smem + 26112);

    f32x4 acct[4][2] = {};
    f32x4 accg[4][2] = {};

    const _Float16* pa  = zht + (size_t)bi * 131072;
    const _Float16* pbv = eht + (size_t)(nj >> 1) * 131072 + (size_t)(nj & 1) * 512;

#define STAGE(KT2, B) { \
        size_t kofs = (size_t)(KT2) * 8192; \
        _Float16* la = (_Float16*)(smem + (B) * 24576); \
        _Float16* lb = (_Float16*)(smem + (B) * 24576 + 16384); \
        gload16(pa + kofs + (size_t)t * 8,         la + t * 8); \
        gload16(pa + kofs + (size_t)(256 + t) * 8, la + (256 + t) * 8); \
        gload16(pa + kofs + (size_t)(512 + t) * 8, la + (512 + t) * 8); \
        gload16(pa + kofs + (size_t)(768 + t) * 8, la + (768 + t) * 8); \
        { int li = t;       gload16(pbv + kofs + (size_t)(li >> 6) * 1024 + (size_t)(li & 63) * 8, lb + li * 8); } \
        { int li = 256 + t; gload16(pbv + kofs + (size_t)(li >> 6) * 1024 + (size_t)(li & 63) * 8, lb + li * 8); } }

    STAGE(0, 0)
    int buf = 0;
    for (int kt2 = 0; kt2 < 16; ++kt2) {
        if (kt2 < 15) {
            // prefetch next tile into the other buffer BEFORE waiting
            STAGE(kt2 + 1, buf ^ 1)
            // wait only for current buffer's 6 loads; leave the 6 prefetch in flight
            asm volatile("s_waitcnt vmcnt(6)" ::: "memory");
        } else {
            asm volatile("s_waitcnt vmcnt(0)" ::: "memory");
        }
        __syncthreads();
        const _Float16* lA = (const _Float16*)(smem + buf * 24576);
        const _Float16* lB = (const _Float16*)(smem + buf * 24576 + 16384);
        f16x8 a0[4], a1[4], b0[2], b1[2];
#pragma unroll
        for (int fr = 0; fr < 4; ++fr) {
            int ro = (wave_r * 64 + fr * 16 + jf) * 8;
            a0[fr] = *(const f16x8*)&lA[g * 1024 + ro];
            a1[fr] = *(const f16x8*)&lA[4096 + g * 1024 + ro];
        }
#pragma unroll
        for (int fc = 0; fc < 2; ++fc) {
            int ro = (wave_c * 32 + fc * 16 + jf) * 8;
            b0[fc] = *(const f16x8*)&lB[g * 512 + ro];
            b1[fc] = *(const f16x8*)&lB[2048 + g * 512 + ro];
        }
        if (kt2 < 8) {
#pragma unroll
            for (int fr = 0; fr < 4; ++fr)
#pragma unroll
            for (int fc = 0; fc < 2; ++fc) {
                acct[fr][fc] = mfma16(a0[fr], b0[fc], acct[fr][fc]);
                acct[fr][fc] = mfma16(a1[fr], b1[fc], acct[fr][fc]);
            }
        } else {
#pragma unroll
            for (int fr = 0; fr < 4; ++fr)
#pragma unroll
            for (int fc = 0; fc < 2; ++fc) {
                accg[fr][fc] = mfma16(a0[fr], b0[fc], accg[fr][fc]);
                accg[fr][fc] = mfma16(a1[fr], b1[fc], accg[fr][fc]);
            }
        }
        __syncthreads();   // all waves done reading buf before it is re-staged
        buf ^= 1;
    }
#undef STAGE

    if (PASS == 2 && t < 64) scol[t] = 0.f;

    const int colbase = nj * 64 + wave_c * 32;
    float e2tc[2], e2gc[2];
#pragma unroll
    for (int fc = 0; fc < 2; ++fc) {
        e2tc[fc] = e2t[colbase + fc * 16 + jf];
        e2gc[fc] = e2g[colbase + fc * 16 + jf];
    }

    if constexpr (PASS == 1) {
        // stage 1: per-row max / top-2 / dt2 / dg2 over this wave's 32 cols; keep l in acct
#pragma unroll
        for (int fr = 0; fr < 4; ++fr) {
#pragma unroll
            for (int reg = 0; reg < 4; ++reg) {
                int rl = wave_r * 64 + fr * 16 + g * 4 + reg;
                int i  = bi * 128 + rl;
                float z2ti = z2t[i], z2gi = z2g[i];
                float mrow = -3.0e38f, dt2 = 0.f, dg2 = 0.f;
                float d1 = 3.0e38f, d2 = 3.0e38f;
                int i1 = 0x7fffffff, i2 = 0x7fffffff;
#pragma unroll
                for (int fc = 0; fc < 2; ++fc) {
                    float ht = acct[fr][fc][reg], hg = accg[fr][fc][reg];
                    float dta = z2ti + e2tc[fc] - ht * (2.0f * INV_HH);
                    float dga = z2gi + e2gc[fc] - hg * (2.0f * INV_HH);
                    float d   = dta + dga;
                    float lv  = -100.0f * d;
                    acct[fr][fc][reg] = lv;
                    dt2 += dta * dta; dg2 += dga * dga;
                    int j = colbase + fc * 16 + jf;
                    top2_point(d1, i1, d2, i2, d, j);
                    mrow = fmaxf(mrow, lv);
                }
#pragma unroll
                for (int s = 1; s < 16; s <<= 1) {
                    mrow = fmaxf(mrow, __shfl_xor(mrow, s));
                    dt2 += __shfl_xor(dt2, s);
                    dg2 += __shfl_xor(dg2, s);
                    float od1 = __shfl_xor(d1, s); int oi1 = __shfl_xor(i1, s);
                    float od2 = __shfl_xor(d2, s); int oi2 = __shfl_xor(i2, s);
                    top2_merge(d1, i1, d2, i2, od1, oi1, od2, oi2);
                }
                if (jf == 0) {
                    sM[rl][wave_c] = mrow; sDt[rl][wave_c] = dt2; sDg[rl][wave_c] = dg2;
                    sD1[rl][wave_c] = d1; sI1[rl][wave_c] = i1;
                    sD2[rl][wave_c] = d2; sI2[rl][wave_c] = i2;
                }
            }
        }
        __syncthreads();
        if (t < 128) sMf[t] = fmaxf(sM[t][0], sM[t][1]);
        __syncthreads();
        // stage 2: Z, S1 vs block max; q into LDS (overlaying dead staging buffers)
#pragma unroll
        for (int fr = 0; fr < 4; ++fr) {
#pragma unroll
            for (int reg = 0; reg < 4; ++reg) {
                int rl = wave_r * 64 + fr * 16 + g * 4 + reg;
                float M = sMf[rl];
                float Z = 0.f, S1 = 0.f;
#pragma unroll
                for (int fc = 0; fc < 2; ++fc) {
                    float lv = acct[fr][fc][reg];
                    float e  = expf(lv - M);
                    Z += e; S1 += e * lv;
                    if constexpr (STOREQ) sQ[rl * 64 + wave_c * 32 + fc * 16 + jf] = f2bf(e);
                }
#pragma unroll
                for (int s = 1; s < 16; s <<= 1) {
                    Z  += __shfl_xor(Z, s);
                    S1 += __shfl_xor(S1, s);
                }
                if (jf == 0) { sZ[rl][wave_c] = Z; sS1[rl][wave_c] = S1; }
            }
        }
        __syncthreads();
        if (t < 128) {
            float M = sMf[t];
            float Z = sZ[t][0] + sZ[t][1];
            float S1 = sS1[t][0] + sS1[t][1];
            float dt2 = sDt[t][0] + sDt[t][1];
            float dg2 = sDg[t][0] + sDg[t][1];
            float d1 = sD1[t][0], d2 = sD2[t][0];
            int i1 = sI1[t][0], i2 = sI2[t][0];
            top2_merge(d1, i1, d2, i2, sD1[t][1], sI1[t][1], sD2[t][1], sI2[t][1]);
            // [nj][row] layout: contiguous 512B runs per array -> no RMW amplification
            size_t pb = (size_t)nj * 8192 + (bi * 128 + t);
            pm[pb] = M; pz[pb] = Z; ps1[pb] = S1;
            pdt[pb] = dt2; pdg[pb] = dg2;
            pd1[pb] = d1; pd2[pb] = d2; pi1[pb] = i1; pi2[pb] = i2;
        }
        if constexpr (STOREQ) {
            // coalesced qm write-out: linear uint4 copy, 128B full-line stores
            const uint4* s4 = (const uint4*)sQ;
#pragma unroll
            for (int it = 0; it < 4; ++it) {
                int f = it * 256 + t;           // [0,1024): 16KB as uint4
                int row = f >> 3, seg = f & 7;  // 8 x 16B = 128B per row
                uint4 q = s4[f];
                *(uint4*)(qm + (size_t)(bi * 128 + row) * 8192 + nj * 64 + seg * 8) = q;
            }
        }
    } else {
        // PASS 2 fallback: recompute p = exp(l - lse), column sums
        float cs0 = 0.f, cs1 = 0.f;
#pragma unroll
        for (int fr = 0; fr < 4; ++fr) {
#pragma unroll
            for (int reg = 0; reg < 4; ++reg) {
                int rl = wave_r * 64 + fr * 16 + g * 4 + reg;
                int i  = bi * 128 + rl;
                float z2ti = z2t[i], z2gi = z2g[i];
                float lsei = lse[i];
#pragma unroll
                for (int fc = 0; fc < 2; ++fc) {
                    float ht = acct[fr][fc][reg], hg = accg[fr][fc][reg];
                    float d = (z2ti + z2gi) + (e2tc[fc] + e2gc[fc])
                            - 2.0f * INV_HH * (ht + hg);
                    float lv = -100.0f * d;
                    float p = expf(lv - lsei);
                    if (fc == 0) cs0 += p; else cs1 += p;
                }
            }
        }
        cs0 += __shfl_xor(cs0, 16); cs0 += __shfl_xor(cs0, 32);
        cs1 += __shfl_xor(cs1, 16); cs1 += __shfl_xor(cs1, 32);
        if (g == 0) {
            atomicAdd(&scol[wave_c * 32 + jf], cs0);
            atomicAdd(&scol[wave_c * 32 + 16 + jf], cs1);
        }
        __syncthreads();
        if (t < 64) atomicAdd(&avgp[nj * 64 + t], scol[t]);
    }
}

// ---- per-row online merge over nj=0..127; coalesced [nj][row] reads ----
__global__ __launch_bounds__(256) void k_rowreduce(
    const float* __restrict__ pm, const float* __restrict__ pz, const float* __restrict__ ps1,
    const float* __restrict__ pdt, const float* __restrict__ pdg,
    float* __restrict__ lse,
    float* __restrict__ rent, float* __restrict__ rdt, float* __restrict__ rdg)
{
    int row = blockIdx.x * 256 + threadIdx.x;
    float m = -3.0e38f, Z = 0.f, S1 = 0.f, dt2 = 0.f, dg2 = 0.f;
#pragma unroll 4
    for (int nj = 0; nj < 128; ++nj) {
        size_t pb = (size_t)nj * 8192 + row;
        float m0 = pm[pb];
        if (m0 > m) {
            float sc = expf(m - m0);
            Z *= sc; S1 *= sc; m = m0;
        }
        float sc0 = expf(m0 - m);
        Z  += pz[pb] * sc0;
        S1 += ps1[pb] * sc0;
        dt2 += pdt[pb]; dg2 += pdg[pb];
    }
    float lseb = m + logf(Z);
    lse[row] = lseb;
    rent[row] = lseb - S1 / Z;
    rdt[row] = dt2; rdg[row] = dg2;
}

// ---- exact-argmin refinement from per-tile top-2 hi-only candidates ----
__global__ __launch_bounds__(256) void k_refine(
    const float* __restrict__ pd1, const float* __restrict__ pd2,
    const int* __restrict__ pi1, const int* __restrict__ pi2,
    const _Float16* __restrict__ zh, const _Float16* __restrict__ zl,
    const _Float16* __restrict__ eh, const _Float16* __restrict__ el,
    const float* __restrict__ z2t, const float* __restrict__ z2g,
    const float* __restrict__ e2t, const float* __restrict__ e2g,
    int* __restrict__ idxi, float* __restrict__ out)
{
    int row = blockIdx.x * 4 + (threadIdx.x >> 6);
    int l = threadIdx.x & 63;
    size_t b0 = (size_t)l * 8192 + row, b1 = (size_t)(l + 64) * 8192 + row;
    float cd[4]; int ci[4];
    cd[0] = pd1[b0]; ci[0] = pi1[b0];
    cd[1] = pd1[b1]; ci[1] = pi1[b1];
    cd[2] = pd2[b0]; ci[2] = pi2[b0];
    cd[3] = pd2[b1]; ci[3] = pi2[b1];
    float M = fminf(fminf(cd[0], cd[1]), fminf(cd[2], cd[3]));
#pragma unroll
    for (int s = 1; s < 64; s <<= 1) M = fminf(M, __shfl_xor(M, s));
    const float eps = 4.0e-3f;
    unsigned long long mk[4];
#pragma unroll
    for (int k = 0; k < 4; ++k) mk[k] = __ballot(cd[k] <= M + eps);

    // preload this row's z chunks: lane l handles chunks 2l, 2l+1 (16 elems)
    float zv[16];
    {
        size_t o0 = tiled_off(row, 2 * l), o1 = tiled_off(row, 2 * l + 1);
        f16x8 h0 = *(const f16x8*)(zh + o0), l0 = *(const f16x8*)(zl + o0);
        f16x8 h1 = *(const f16x8*)(zh + o1), l1 = *(const f16x8*)(zl + o1);
#pragma unroll
        for (int e = 0; e < 8; ++e) {
            zv[e]     = (float)h0[e] * (1.0f/256.0f) + (float)l0[e] * (1.0f/1048576.0f);
            zv[8 + e] = (float)h1[e] * (1.0f/256.0f) + (float)l1[e] * (1.0f/1048576.0f);
        }
    }
    float zz = z2t[row] + z2g[row];
    float bd = 3.0e38f; int bj = 0x7fffffff;
#pragma unroll 1
    for (int k = 0; k < 4; ++k) {
        while (mk[k]) {
            int s = (int)__ffsll(mk[k]) - 1; mk[k] &= mk[k] - 1;
            int cand = __shfl(ci[k], s);
            size_t o0 = tiled_off(cand, 2 * l), o1 = tiled_off(cand, 2 * l + 1);
            f16x8 h0 = *(const f16x8*)(eh + o0), l0 = *(const f16x8*)(el + o0);
            f16x8 h1 = *(const f16x8*)(eh + o1), l1 = *(const f16x8*)(el + o1);
            float dot = 0.f;
#pragma unroll
            for (int e = 0; e < 8; ++e) {
                float ev0 = (float)h0[e] * (1.0f/256.0f) + (float)l0[e] * (1.0f/1048576.0f);
                float ev1 = (float)h1[e] * (1.0f/256.0f) + (float)l1[e] * (1.0f/1048576.0f);
                dot += zv[e] * ev0 + zv[8 + e] * ev1;
            }
#pragma unroll
            for (int s2 = 1; s2 < 64; s2 <<= 1) dot += __shfl_xor(dot, s2);
            float d = zz + e2t[cand] + e2g[cand] - 2.0f * dot;
            if (d < bd || (d == bd && cand < bj)) { bd = d; bj = cand; }
        }
    }
    if (l == 0) { idxi[row] = bj; out[O_IX + row] = (float)bj; }
}

// ---- stored-q column sums, atomic-free; scale computed inline from pm/lse ----
__global__ __launch_bounds__(256) void k_colsum(const unsigned short* __restrict__ qm,
                                                const float* __restrict__ pm,
                                                const float* __restrict__ lse,
                                                float* __restrict__ avg4) {
    int cc = blockIdx.x, rb = blockIdx.y, t = threadIdx.x;
    int cp = t & 31, rg = t >> 5;
    float a0 = 0.f, a1 = 0.f;
    const unsigned short* qb = qm + (size_t)cc * 64 + (size_t)cp * 2;
    const float* pmb = pm + (size_t)cc * 8192;
#pragma unroll 4
    for (int rr = rg; rr < 1024; rr += 8) {
        int r = rb * 1024 + rr;
        float s = expf(pmb[r] - lse[r]);   // broadcast loads (all lanes same r)
        unsigned int q = *(const unsigned int*)(qb + (size_t)r * 8192);
        a0 += bf2f((unsigned short)(q & 0xffffu)) * s;
        a1 += bf2f((unsigned short)(q >> 16)) * s;
    }
    __shared__ float red[512];
    red[rg * 64 + cp * 2] = a0; red[rg * 64 + cp * 2 + 1] = a1;
    __syncthreads();
    if (rg == 0) {
        float s0 = 0.f, s1 = 0.f;
#pragma unroll
        for (int k = 0; k < 8; ++k) { s0 += red[k * 64 + cp * 2]; s1 += red[k * 64 + cp * 2 + 1]; }
        avg4[(size_t)rb * 8192 + cc * 64 + cp * 2]     = s0;
        avg4[(size_t)rb * 8192 + cc * 64 + cp * 2 + 1] = s1;
    }
}

// ---- gather z_q outputs + per-row vq sums ----
__global__ __launch_bounds__(1024) void k_gather(
    const _Float16* __restrict__ zh, const _Float16* __restrict__ zl,
    const _Float16* __restrict__ eh, const _Float16* __restrict__ el,
    const int* __restrict__ idxi, float* __restrict__ out, float* __restrict__ gvq)
{
    int t = threadIdx.x;
    int r8 = t & 7, ck = t >> 3;
    int b = blockIdx.x * 8 + r8;
    int idx = idxi[b];
    size_t zo = tiled_off(b, ck), eo = tiled_off(idx, ck);
    f16x8 zh8 = *(const f16x8*)(zh + zo);
    f16x8 zl8 = *(const f16x8*)(zl + zo);
    f16x8 eh8 = *(const f16x8*)(eh + eo);
    f16x8 el8 = *(const f16x8*)(el + eo);
    float ss = 0.f; float oz[8], zq[8];
#pragma unroll
    for (int e = 0; e < 8; ++e) {
        float zn = ((float)zh8[e] + (float)zl8[e] * (1.0f / 4096.0f)) * (1.0f / SCL_H);
        float eq = ((float)eh8[e] + (float)el8[e] * (1.0f / 4096.0f)) * (1.0f / SCL_H);
        float df = eq - zn;
        zq[e] = eq; oz[e] = zn + df; ss += df * df;
    }
    float* dst = out + (size_t)b * 1024 + (size_t)ck * 8;
    *(float4*)dst       = make_float4(oz[0], oz[1], oz[2], oz[3]);
    *(float4*)(dst + 4) = make_float4(oz[4], oz[5], oz[6], oz[7]);
    float* tg = (ck < 64) ? (out + O_ZT + (size_t)b * 512 + (size_t)ck * 8)
                          : (out + O_ZG + (size_t)b * 512 + (size_t)(ck - 64) * 8);
    *(float4*)tg       = make_float4(zq[0], zq[1], zq[2], zq[3]);
    *(float4*)(tg + 4) = make_float4(zq[4], zq[5], zq[6], zq[7]);
    __shared__ float red[8*132];
    int ri = r8 * 132 + ck;
    red[ri] = ss; __syncthreads();
    for (int s = 64; s > 0; s >>= 1) { if (ck < s) red[ri] += red[ri + s]; __syncthreads(); }
    if (ck == 0) gvq[b] = red[ri];
}

__global__ __launch_bounds__(256) void k_finalize(const float* __restrict__ avg4,
        const float* __restrict__ rent, const float* __restrict__ rdt,
        const float* __restrict__ rdg, const float* __restrict__ gvq,
        float* __restrict__ out) {
    int t = threadIdx.x;
    float ent = 0.f, se = 0.f, dt = 0.f, dg = 0.f, vq = 0.f;
    for (int n = t; n < 8192; n += 256) {
        float a = 0.f;
#pragma unroll
        for (int k = 0; k < 8; ++k) a += avg4[(size_t)k * 8192 + n];
        a *= (1.0f / 8192.0f);
        ent -= a * logf(a + 1e-5f);
        se += rent[n]; dt += rdt[n]; dg += rdg[n]; vq += gvq[n];
    }
    __shared__ float red[256];
#define RED(x) { red[t] = x; __syncthreads(); \
    for (int s = 128; s > 0; s >>= 1) { if (t < s) red[t] += red[t + s]; __syncthreads(); } \
    x = red[0]; __syncthreads(); }
    RED(ent) RED(se) RED(dt) RED(dg) RED(vq)
#undef RED
    if (t == 0) {
        float vqm = vq * (1.0f / 8388608.0f);
        out[O_VQ]  = vqm;
        out[O_CM]  = 0.25f * vqm;
        out[O_ENT] = 0.1f * (se * (1.0f / 8192.0f) - ent);
        out[O_TD]  = dt * (1.0f / 8192.0f);
        out[O_GD]  = dg * (1.0f / 8192.0f);
    }
}

extern "C" void kernel_launch(void* const* d_in, const int* in_sizes, int n_in,
                              void* d_out, int out_size, void* d_ws, size_t ws_size,
                              hipStream_t stream) {
    const float* z  = (const float*)d_in[0];
    const float* et = (const float*)d_in[1];
    const float* eg = (const float*)d_in[2];
    float* out = (float*)d_out;
    float* ws  = (float*)d_ws;

    _Float16* zh = (_Float16*)(ws + WS_ZH);
    _Float16* zl = (_Float16*)(ws + WS_ZL);
    _Float16* eh = (_Float16*)(ws + WS_EH);
    _Float16* el = (_Float16*)(ws + WS_EL);
    float* z2t = ws + WS_Z2T;
    float* z2g = ws + WS_Z2G;
    float* e2t = ws + WS_E2T;
    float* e2g = ws + WS_E2G;
    float* pm  = ws + WS_PM;
    float* pz  = ws + WS_PZ;
    float* ps1 = ws + WS_PS1;
    float* pdt = ws + WS_PDT;
    float* pdg = ws + WS_PDG;
    float* pd1 = ws + WS_PD1;
    float* pd2 = ws + WS_PD2;
    int*   pi1 = (int*)(ws + WS_PI1);
    int*   pi2 = (int*)(ws + WS_PI2);
    float* lsep = ws + WS_LSE;
    int*   idxi = (int*)(ws + WS_IDX);
    float* rent = ws + WS_RENT;
    float* rdt  = ws + WS_RDT;
    float* rdg  = ws + WS_RDG;
    float* gvq  = ws + WS_GVQ;
    float* avg4 = ws + WS_AVG4;
    unsigned short* qm = (unsigned short*)(ws + WS_QM);

    bool storeq = (ws_size >= WS_STORE_END * sizeof(float));

    k_norm_z<<<1024, 1024, 0, stream>>>(z, zh, zl, z2t, z2g);
    k_norm_e<<<1024, 1024, 0, stream>>>(et, eg, eh, el, e2t, e2g);

    if (storeq) {
        k_gemm<1, true><<<8192, 256, 0, stream>>>(zh, eh, z2t, z2g, e2t, e2g,
                                                  pm, pz, ps1, pdt, pdg,
                                                  pd1, pd2, pi1, pi2, qm, lsep, avg4);
    } else {
        k_gemm<1, false><<<8192, 256, 0, stream>>>(zh, eh, z2t, z2g, e2t, e2g,
                                                   pm, pz, ps1, pdt, pdg,
                                                   pd1, pd2, pi1, pi2, qm, lsep, avg4);
    }
    k_rowreduce<<<32, 256, 0, stream>>>(pm, pz, ps1, pdt, pdg,
                                        lsep, rent, rdt, rdg);
    k_refine<<<2048, 256, 0, stream>>>(pd1, pd2, pi1, pi2, zh, zl, eh, el,
                                       z2t, z2g, e2t, e2g, idxi, out);
    if (storeq) {
        k_colsum<<<dim3(128, 8), 256, 0, stream>>>(qm, pm, lsep, avg4);
    } else {
        k_zero<<<256, 256, 0, stream>>>(avg4, 65536);
        k_gemm<2, false><<<8192, 256, 0, stream>>>(zh, eh, z2t, z2g, e2t, e2g,
                                                   pm, pz, ps1, pdt, pdg,
                                                   pd1, pd2, pi1, pi2, qm, lsep, avg4);
    }
    k_gather<<<1024, 1024, 0, stream>>>(zh, zl, eh, el, idxi, out, gvq);
    k_finalize<<<1, 256, 0, stream>>>(avg4, rent, rdt, rdg, gvq, out);
}